// Round 8
// baseline (809.534 us; speedup 1.0000x reference)
//
#include <hip/hip_runtime.h>
#include <hip/hip_bf16.h>
#include <math.h>

// ConformHopfieldBatch: B=4 S=2048 IN=64 D=128 HID=400 H=4 K=20 NQ=18
// softmax monotone -> top_k(assoc) == top_k(raw scores). bf16-hi MFMA
// PREFILTER (A=K,B=Q swap; lane owns its q-row's scores in-register) ->
// approx candidates; exact fp32 RESCORE selects the true top-20 (R2 lesson).
// R7 postmortem: (a) k_mlp grid-capped at 2 waves/SIMD -> R8 4 rows/block,
// grid 4096 (4 waves/SIMD); per-row FMA order unchanged -> bit-identical.
// (b) scan+select stuck ~350us vs ~70us VALU model across 3 rewrites ->
// I-CACHE: fully-unrolled scan body (~5k instrs ~40KB) >> 32KB I$ -> R8
// rolls the tile loop (body ~1.4KB); bubble/reg loops stay unrolled (static
// register indexing). k_select rescore loop rolled too. Zero semantic change.

#define SS 2048

typedef short short8v __attribute__((ext_vector_type(8)));
typedef float float4v __attribute__((ext_vector_type(4)));

__constant__ float c_alphas[18] = {0.05f,0.06f,0.08f,0.1f,0.12f,0.14f,0.15f,0.17f,
                                   0.19f,0.2f,0.21f,0.23f,0.25f,0.3f,0.35f,0.38f,0.4f,0.45f};

// output flat offsets (return-order concat)
#define OFF_Y      1
#define OFF_YPRED  32769
#define OFF_YLOW   65537ll
#define OFF_YHIGH  655361ll
#define OFF_ERR    1245185ll
#define OFF_QLOW   1253377ll
#define OFF_QHIGH  1843201ll

__device__ inline short f2bf_s(float f) {
    __hip_bfloat16 h = __float2bfloat16(f);
    return __builtin_bit_cast(short, h);
}
// monotone fp32 -> u32 map (order-preserving)
__device__ inline unsigned mono(float f) {
    unsigned u = __builtin_bit_cast(unsigned, f);
    return (u & 0x80000000u) ? ~u : (u | 0x80000000u);
}
// wave-uniform register broadcast (v_readlane_b32)
__device__ inline float rdlane(float v, int l) {
    return __builtin_bit_cast(float, __builtin_amdgcn_readlane(__builtin_bit_cast(int, v), l));
}

// ---------------------------------------------------------------------------
// Kernel A: fused MLP + LayerNorm + projection. 64 threads, 4 rows/block.
// Activations register-resident: lane t holds cols {c*64+t} of every row;
// broadcast via readlane. No LDS. blocks 0..2047: true->q; 2048..4095: sim->k.
// Head-major fp32 out [(b*4+h)][s][128]; bf16-hi of k for the MFMA scan.
// ---------------------------------------------------------------------------
__global__ __launch_bounds__(64) void k_mlp(
    const float* __restrict__ Xt, const float* __restrict__ Xs,
    const float* __restrict__ W1, const float* __restrict__ b1,
    const float* __restrict__ W2, const float* __restrict__ b2,
    const float* __restrict__ W3, const float* __restrict__ b3,
    const float* __restrict__ W4, const float* __restrict__ b4,
    const float* __restrict__ Wq, const float* __restrict__ bq,
    const float* __restrict__ Wk, const float* __restrict__ bk,
    const float* __restrict__ g_q, const float* __restrict__ beta_q,
    const float* __restrict__ g_k, const float* __restrict__ beta_k,
    float* __restrict__ qf, float* __restrict__ kf,
    __hip_bfloat16* __restrict__ khi)
{
    const int t    = threadIdx.x;          // 0..63
    const int bi   = blockIdx.x;
    const int half = bi >> 11;             // 0:true/q 1:sim/k
    const int rbase = (bi & 2047) * 4;     // row group within half
    const float* X = half ? Xs : Xt;

    int jm[7];                             // clamped col ids for 400-wide layers
    #pragma unroll
    for (int cc = 0; cc < 7; ++cc) { int j = cc*64 + t; jm[cc] = (j < 400) ? j : 399; }

    // input rows into registers: lane t holds x[r][t]
    float xreg[4];
    #pragma unroll
    for (int r = 0; r < 4; ++r) xreg[r] = X[(size_t)(rbase + r)*64 + t];

    float A1[4][7], A2[4][7];

    // ---- layer 1: 64 -> 400 (relu), xreg -> A1 ----
    {
        #pragma unroll
        for (int r = 0; r < 4; ++r)
            #pragma unroll
            for (int cc = 0; cc < 7; ++cc) A1[r][cc] = 0.f;
        #pragma unroll 4
        for (int il = 0; il < 64; ++il) {
            float wv[7];
            #pragma unroll
            for (int cc = 0; cc < 7; ++cc) wv[cc] = W1[il*400 + jm[cc]];
            #pragma unroll
            for (int r = 0; r < 4; ++r) {
                const float x = rdlane(xreg[r], il);
                #pragma unroll
                for (int cc = 0; cc < 7; ++cc) A1[r][cc] = fmaf(x, wv[cc], A1[r][cc]);
            }
        }
        #pragma unroll
        for (int cc = 0; cc < 7; ++cc) {
            const float bb = b1[jm[cc]];
            #pragma unroll
            for (int r = 0; r < 4; ++r) A1[r][cc] = fmaxf(A1[r][cc] + bb, 0.f);
        }
    }

    // ---- layer 2: 400 -> 400 (relu), A1 -> A2 ----
    {
        #pragma unroll
        for (int r = 0; r < 4; ++r)
            #pragma unroll
            for (int cc = 0; cc < 7; ++cc) A2[r][cc] = 0.f;
        #pragma unroll
        for (int cs = 0; cs < 7; ++cs) {
            const int ilim = (cs == 6) ? 16 : 64;
            #pragma unroll 4
            for (int il = 0; il < ilim; ++il) {
                const int i = cs*64 + il;
                float wv[7];
                #pragma unroll
                for (int cc = 0; cc < 7; ++cc) wv[cc] = W2[i*400 + jm[cc]];
                #pragma unroll
                for (int r = 0; r < 4; ++r) {
                    const float x = rdlane(A1[r][cs], il);
                    #pragma unroll
                    for (int cc = 0; cc < 7; ++cc) A2[r][cc] = fmaf(x, wv[cc], A2[r][cc]);
                }
            }
        }
        #pragma unroll
        for (int cc = 0; cc < 7; ++cc) {
            const float bb = b2[jm[cc]];
            #pragma unroll
            for (int r = 0; r < 4; ++r) A2[r][cc] = fmaxf(A2[r][cc] + bb, 0.f);
        }
    }

    // ---- layer 3: 400 -> 400 (relu), A2 -> A1 ----
    {
        #pragma unroll
        for (int r = 0; r < 4; ++r)
            #pragma unroll
            for (int cc = 0; cc < 7; ++cc) A1[r][cc] = 0.f;
        #pragma unroll
        for (int cs = 0; cs < 7; ++cs) {
            const int ilim = (cs == 6) ? 16 : 64;
            #pragma unroll 4
            for (int il = 0; il < ilim; ++il) {
                const int i = cs*64 + il;
                float wv[7];
                #pragma unroll
                for (int cc = 0; cc < 7; ++cc) wv[cc] = W3[i*400 + jm[cc]];
                #pragma unroll
                for (int r = 0; r < 4; ++r) {
                    const float x = rdlane(A2[r][cs], il);
                    #pragma unroll
                    for (int cc = 0; cc < 7; ++cc) A1[r][cc] = fmaf(x, wv[cc], A1[r][cc]);
                }
            }
        }
        #pragma unroll
        for (int cc = 0; cc < 7; ++cc) {
            const float bb = b3[jm[cc]];
            #pragma unroll
            for (int r = 0; r < 4; ++r) A1[r][cc] = fmaxf(A1[r][cc] + bb, 0.f);
        }
    }

    // ---- layer 4: 400 -> 128 (no relu), A1 -> acc4 (lane t: cols t, 64+t) ----
    float acc4[4][2];
    {
        #pragma unroll
        for (int r = 0; r < 4; ++r) { acc4[r][0] = 0.f; acc4[r][1] = 0.f; }
        #pragma unroll
        for (int cs = 0; cs < 7; ++cs) {
            const int ilim = (cs == 6) ? 16 : 64;
            #pragma unroll 4
            for (int il = 0; il < ilim; ++il) {
                const int i = cs*64 + il;
                const float w0 = W4[i*128 + t];
                const float w1 = W4[i*128 + 64 + t];
                #pragma unroll
                for (int r = 0; r < 4; ++r) {
                    const float x = rdlane(A1[r][cs], il);
                    acc4[r][0] = fmaf(x, w0, acc4[r][0]);
                    acc4[r][1] = fmaf(x, w1, acc4[r][1]);
                }
            }
        }
        const float bb0 = b4[t], bb1 = b4[64 + t];
        #pragma unroll
        for (int r = 0; r < 4; ++r) { acc4[r][0] += bb0; acc4[r][1] += bb1; }
    }

    // ---- LayerNorm over 128 (values spread: 2/lane x 64 lanes) ----
    float lnv[4][2];
    {
        const float* g  = half ? g_k : g_q;
        const float* be = half ? beta_k : beta_q;
        const float gl0 = g[t],  gl1 = g[64 + t];
        const float bl0 = be[t], bl1 = be[64 + t];
        #pragma unroll
        for (int r = 0; r < 4; ++r) {
            float s = acc4[r][0] + acc4[r][1];
            #pragma unroll
            for (int o = 32; o > 0; o >>= 1) s += __shfl_xor(s, o);
            const float mu = s * (1.f/128.f);
            const float d0 = acc4[r][0] - mu, d1 = acc4[r][1] - mu;
            float vs = d0*d0 + d1*d1;
            #pragma unroll
            for (int o = 32; o > 0; o >>= 1) vs += __shfl_xor(vs, o);
            const float rstd = rsqrtf(vs * (1.f/128.f) + 1e-5f);
            lnv[r][0] = d0*rstd*gl0 + bl0;
            lnv[r][1] = d1*rstd*gl1 + bl1;
        }
    }

    // ---- projection 128 -> 512 (8 cols/lane), write fp32 (+bf16-hi for k) ----
    {
        const float* Wp = half ? Wk : Wq;
        const float* bp = half ? bk : bq;
        float* of = half ? kf : qf;
        float accp[4][8];
        #pragma unroll
        for (int r = 0; r < 4; ++r)
            #pragma unroll
            for (int cc = 0; cc < 8; ++cc) accp[r][cc] = 0.f;
        #pragma unroll
        for (int cs = 0; cs < 2; ++cs) {
            #pragma unroll 4
            for (int il = 0; il < 64; ++il) {
                const int i = cs*64 + il;
                float wv[8];
                #pragma unroll
                for (int cc = 0; cc < 8; ++cc) wv[cc] = Wp[i*512 + cc*64 + t];
                #pragma unroll
                for (int r = 0; r < 4; ++r) {
                    const float x = rdlane(lnv[r][cs], il);
                    #pragma unroll
                    for (int cc = 0; cc < 8; ++cc) accp[r][cc] = fmaf(x, wv[cc], accp[r][cc]);
                }
            }
        }
        float bpv[8];
        #pragma unroll
        for (int cc = 0; cc < 8; ++cc) bpv[cc] = bp[cc*64 + t];
        #pragma unroll
        for (int r = 0; r < 4; ++r) {
            const int gidx = rbase + r;
            const int bb = gidx >> 11, s = gidx & 2047;
            #pragma unroll
            for (int cc = 0; cc < 8; ++cc) {
                const int j  = cc*64 + t;
                const int hh = j >> 7, d = j & 127;
                const float v = accp[r][cc] + bpv[cc];
                const size_t dst = ((size_t)(bb*4 + hh)*2048 + s)*128 + d;
                of[dst] = v;
                if (half) khi[dst] = __float2bfloat16(v);
            }
        }
    }
}

// ---------------------------------------------------------------------------
// Kernel B: MFMA scan over an m-quarter (512 cols) + branchless per-quad
// register top-20 + per-row owner merge -> approx-top-24 keys to ws.
// Block = (stile, hb, mq). Tile loop ROLLED (I-cache); bubble unrolled
// (static register indexing). Keys: (mono(score)&~0x7FF)|col.
// ---------------------------------------------------------------------------
__global__ __launch_bounds__(256) void k_scan(
    const float* __restrict__ qf, const __hip_bfloat16* __restrict__ khi,
    unsigned* __restrict__ wsk)
{
    __shared__ unsigned kd[64*4*21];   // 21.5KB lane-list dump (pad 21)

    const int tid   = threadIdx.x;
    const int stile = blockIdx.x;      // 0..31
    const int hb    = blockIdx.y;      // 0..15
    const int mq    = blockIdx.z;      // 0..3

    const int lane = tid & 63;
    const int w    = tid >> 6;
    const int m16  = lane & 15;
    const int quad = lane >> 4;

    const size_t slab = (size_t)hb * 2048;
    const __hip_bfloat16* slabp = khi + slab*128;

    const int sg_my = stile*64 + w*16 + m16;

    // Q fragment (B operand): B[n=m16][k=quad*8+j+ks*32] = q[w*16+n][k]
    short8v bq_[4];
    {
        const float* qp = qf + (slab + sg_my)*128 + quad*8;
        #pragma unroll
        for (int ks = 0; ks < 4; ++ks) {
            const float4 x0 = *(const float4*)(qp + ks*32);
            const float4 x1 = *(const float4*)(qp + ks*32 + 4);
            short8v tt;
            tt[0]=f2bf_s(x0.x); tt[1]=f2bf_s(x0.y); tt[2]=f2bf_s(x0.z); tt[3]=f2bf_s(x0.w);
            tt[4]=f2bf_s(x1.x); tt[5]=f2bf_s(x1.y); tt[6]=f2bf_s(x1.z); tt[7]=f2bf_s(x1.w);
            bq_[ks] = tt;
        }
    }

    unsigned keys[20];                 // ascending; keys[0] = min
    #pragma unroll
    for (int n = 0; n < 20; ++n) keys[n] = 0u;

    #pragma unroll 1
    for (int cti = 0; cti < 32; ++cti) {
        const int colb = mq*512 + cti*16;
        const __hip_bfloat16* kp = slabp + (size_t)(colb + m16)*128 + quad*8;
        float4v acc = (float4v){0.f,0.f,0.f,0.f};
        #pragma unroll
        for (int ks = 0; ks < 4; ++ks) {
            const short8v ka = *(const short8v*)(kp + ks*32);
            acc = __builtin_amdgcn_mfma_f32_16x16x32_bf16(ka, bq_[ks], acc, 0, 0, 0);
        }
        const int cb = colb + quad*4;
        #pragma unroll
        for (int reg = 0; reg < 4; ++reg) {
            const int m = cb + reg;
            unsigned key = (mono(acc[reg]) & 0xFFFFF800u) | (unsigned)m;
            key = (m == sg_my) ? 0u : key;              // diagonal excluded
            keys[0] = (key > keys[0]) ? key : keys[0];  // drop-min insert
            #pragma unroll
            for (int i = 0; i < 19; ++i) {              // bubble restores order
                const unsigned a = keys[i], c = keys[i+1];
                keys[i]   = (a < c) ? a : c;
                keys[i+1] = (a < c) ? c : a;
            }
        }
    }

    // dump descending per (row, quad)
    const int rr = w*16 + m16;
    #pragma unroll
    for (int n = 0; n < 20; ++n)
        kd[(rr*4 + quad)*21 + n] = keys[19 - n];
    __syncthreads();

    // owner (quad 0): merge 4 sorted-desc 20-lists -> top-24 -> ws (desc)
    if (quad == 0) {
        const unsigned* L0 = &kd[(rr*4 + 0)*21];
        const unsigned* L1 = &kd[(rr*4 + 1)*21];
        const unsigned* L2 = &kd[(rr*4 + 2)*21];
        const unsigned* L3 = &kd[(rr*4 + 3)*21];
        int p0 = 0, p1 = 0, p2 = 0, p3 = 0;
        const size_t base = (size_t)hb*2048 + stile*64 + rr;
        #pragma unroll 1
        for (int n = 0; n < 24; ++n) {
            const unsigned h0 = (p0 < 20) ? L0[p0] : 0u;
            const unsigned h1 = (p1 < 20) ? L1[p1] : 0u;
            const unsigned h2 = (p2 < 20) ? L2[p2] : 0u;
            const unsigned h3 = (p3 < 20) ? L3[p3] : 0u;
            unsigned bv = h0; int bs = 0;
            if (h1 > bv) { bv = h1; bs = 1; }
            if (h2 > bv) { bv = h2; bs = 2; }
            if (h3 > bv) { bv = h3; bs = 3; }
            if (bs == 0) ++p0; else if (bs == 1) ++p1; else if (bs == 2) ++p2; else ++p3;
            wsk[(size_t)(mq*24 + n)*32768 + base] = bv;
        }
    }
}

// ---------------------------------------------------------------------------
// Kernel C: per row merge 4x24 approx keys -> top-32 -> cooperative exact
// fp32 rescore (4 lanes/row, coalesced segments, butterfly reduce) -> exact
// top-20 -> quantiles + outputs + score accumulation.
// Block = (stile, hb), 64 rows. Rescore loop rolled (I-cache).
// ---------------------------------------------------------------------------
__global__ __launch_bounds__(256) void k_select(
    const float* __restrict__ qf, const float* __restrict__ kf,
    const unsigned* __restrict__ wsk,
    const float* __restrict__ errors, const float* __restrict__ y,
    const float* __restrict__ y_pred,
    float* __restrict__ out, float* __restrict__ hacc)
{
    __shared__ unsigned kd[64*4*25];       // 25.6KB (pad 25)
    __shared__ unsigned short cb[64*33];   // 4.2KB candidate cols
    __shared__ float es[64*33];            // 8.4KB exact scores
    __shared__ float ebuf[64*21];          // 5.4KB sort buffer

    const int tid   = threadIdx.x;
    const int stile = blockIdx.x;          // 0..31
    const int hb    = blockIdx.y;          // 0..15
    const int b     = hb >> 2;
    const int h     = hb & 3;

    const int lane = tid & 63;
    const int w    = tid >> 6;
    const int m16  = lane & 15;
    const int quad = lane >> 4;
    const int rr   = w*16 + m16;
    const int sg   = stile*64 + rr;

    const size_t base = (size_t)hb*2048 + sg;
    // lane loads mq=quad's 24 keys (coalesced across rows)
    #pragma unroll 1
    for (int n = 0; n < 24; ++n)
        kd[(rr*4 + quad)*25 + n] = wsk[(size_t)(quad*24 + n)*32768 + base];
    __syncthreads();

    // owner: merge 4 sorted-desc 24-lists -> approx-top-32 cols
    if (quad == 0) {
        const unsigned* L0 = &kd[(rr*4 + 0)*25];
        const unsigned* L1 = &kd[(rr*4 + 1)*25];
        const unsigned* L2 = &kd[(rr*4 + 2)*25];
        const unsigned* L3 = &kd[(rr*4 + 3)*25];
        int p0 = 0, p1 = 0, p2 = 0, p3 = 0;
        #pragma unroll 1
        for (int n = 0; n < 32; ++n) {
            const unsigned h0 = (p0 < 24) ? L0[p0] : 0u;
            const unsigned h1 = (p1 < 24) ? L1[p1] : 0u;
            const unsigned h2 = (p2 < 24) ? L2[p2] : 0u;
            const unsigned h3 = (p3 < 24) ? L3[p3] : 0u;
            unsigned bv = h0; int bs = 0;
            if (h1 > bv) { bv = h1; bs = 1; }
            if (h2 > bv) { bv = h2; bs = 2; }
            if (h3 > bv) { bv = h3; bs = 3; }
            if (bs == 0) ++p0; else if (bs == 1) ++p1; else if (bs == 2) ++p2; else ++p3;
            cb[rr*33 + n] = (unsigned short)(bv & 0x7FFu);
        }
    }
    __syncthreads();

    // cooperative exact rescore of the 32 candidates
    const size_t slab = (size_t)hb * 2048;
    const float* qrow_p = qf + (slab + sg)*128;
    float4 qseg[8];
    #pragma unroll
    for (int u = 0; u < 8; ++u)
        qseg[u] = *(const float4*)(qrow_p + quad*4 + u*16);
    const float* kslab = kf + slab*128;
    #pragma unroll 1
    for (int n = 0; n < 32; ++n) {
        const int col = cb[rr*33 + n];
        const float* kc = kslab + (size_t)col*128 + quad*4;
        float4v s = (float4v){0.f,0.f,0.f,0.f};
        #pragma unroll
        for (int u = 0; u < 8; ++u) {
            const float4 kv = *(const float4*)(kc + u*16);
            s[0] = fmaf(qseg[u].x, kv.x, s[0]);
            s[1] = fmaf(qseg[u].y, kv.y, s[1]);
            s[2] = fmaf(qseg[u].z, kv.z, s[2]);
            s[3] = fmaf(qseg[u].w, kv.w, s[3]);
        }
        float v = (s[0] + s[1]) + (s[2] + s[3]);
        v += __shfl_xor(v, 16);
        v += __shfl_xor(v, 32);
        if (quad == 0) es[rr*33 + n] = v;
    }

    // owner: exact top-20 selection (desc, col asc ties) + quantiles
    float sq = 0.f;
    if (quad == 0) {
        float* e = &ebuf[rr*21];
        #pragma unroll 1
        for (int k = 0; k < 20; ++k) {
            float best = -INFINITY; int bc = 4096, bj = 0;
            #pragma unroll 1
            for (int j = 0; j < 32; ++j) {
                const float v = es[rr*33 + j];
                const int c = cb[rr*33 + j];
                if (v > best || (v == best && c < bc)) { best = v; bc = c; bj = j; }
            }
            es[rr*33 + bj] = -INFINITY;
            e[k] = errors[((size_t)(b*SS + bc))*4];   // errors[..., 0]
        }
        #pragma unroll 1
        for (int a = 1; a < 20; ++a) {     // insertion sort ascending
            const float v = e[a];
            int n = a;
            while (n > 0 && e[n-1] > v) { e[n] = e[n-1]; --n; }
            e[n] = v;
        }
        const float yp = y_pred[((size_t)(b*SS + sg))*4];
        const float yt = y[((size_t)(b*SS + sg))*4];
        float msum = 0.f;
        const size_t obase = ((size_t)(h*4 + b)*18)*2048 + sg;
        #pragma unroll 1
        for (int a = 0; a < 18; ++a) {
            const float alpha = c_alphas[a];
            const float beta  = 0.5f*alpha;
            const float pl = beta * 19.f;
            const int   il = (int)pl;
            const float fl = pl - (float)il;
            const float ql = e[il]*(1.f-fl) + e[il+1]*fl;
            const float qq = (1.f - alpha) + beta;
            const float ph = qq * 19.f;
            const int   ih = (int)ph;
            const float fh = ph - (float)ih;
            const float qh = e[ih]*(1.f-fh) + e[ih+1]*fh;
            msum += ql + qh;
            const size_t oidx = obase + (size_t)a*2048;
            out[OFF_YLOW  + oidx] = ql + yp;
            out[OFF_YHIGH + oidx] = qh + yp;
            out[OFF_QLOW  + oidx] = ql;
            out[OFF_QHIGH + oidx] = qh;
        }
        const float me = msum * (1.f/36.f);
        const float dd = yt - (me + yp);
        sq = dd*dd;
    }
    // wave-reduce sq (non-owners contribute 0), one atomic per wave
    #pragma unroll
    for (int o = 32; o > 0; o >>= 1) sq += __shfl_xor(sq, o);
    if (lane == 0) atomicAdd(&hacc[h], sq);
}

__global__ void k_init(float* __restrict__ hacc) {
    if (threadIdx.x < 4) hacc[threadIdx.x] = 0.f;
}

__global__ __launch_bounds__(256) void k_finalize(
    const float* __restrict__ y, const float* __restrict__ y_pred,
    const float* __restrict__ errors, const float* __restrict__ hacc,
    float* __restrict__ out)
{
    const int i = blockIdx.x*256 + threadIdx.x;
    if (i == 0)
        out[0] = (hacc[0]+hacc[1]+hacc[2]+hacc[3]) * (1.f/32768.f);
    if (i < 32768)      out[OFF_Y + i] = y[i];
    else if (i < 65536) out[OFF_YPRED + (i - 32768)] = y_pred[i - 32768];
    else if (i < 73728) { const int j = i - 65536; out[OFF_ERR + j] = errors[(size_t)j*4]; }
}

extern "C" void kernel_launch(void* const* d_in, const int* in_sizes, int n_in,
                              void* d_out, int out_size, void* d_ws, size_t ws_size,
                              hipStream_t stream)
{
    const float* Xt     = (const float*)d_in[0];
    const float* Xs     = (const float*)d_in[1];
    const float* errors = (const float*)d_in[2];
    const float* y      = (const float*)d_in[3];
    const float* y_pred = (const float*)d_in[4];
    const float* W1 = (const float*)d_in[5];   const float* b1 = (const float*)d_in[6];
    const float* W2 = (const float*)d_in[7];   const float* b2 = (const float*)d_in[8];
    const float* W3 = (const float*)d_in[9];   const float* b3 = (const float*)d_in[10];
    const float* W4 = (const float*)d_in[11];  const float* b4 = (const float*)d_in[12];
    const float* Wq = (const float*)d_in[13];  const float* bq = (const float*)d_in[14];
    const float* Wk = (const float*)d_in[15];  const float* bk = (const float*)d_in[16];
    const float* g_q    = (const float*)d_in[17];
    const float* beta_q = (const float*)d_in[18];
    const float* g_k    = (const float*)d_in[19];
    const float* beta_k = (const float*)d_in[20];

    float* out  = (float*)d_out;
    char*  base = (char*)d_ws;
    const size_t SLAB = (size_t)16*2048*128;               // 4,194,304 elements
    float* hacc = (float*)base;                            // 64B slot
    float* qf   = (float*)(base + 256);                    // 16MB
    float* kf   = qf + SLAB;                               // 16MB
    __hip_bfloat16* khi = (__hip_bfloat16*)(kf + SLAB);    // 8MB
    unsigned* wsk = (unsigned*)(khi + SLAB);               // 4*24*32768 u32 = 12.6MB

    k_init<<<1, 64, 0, stream>>>(hacc);
    k_mlp<<<4096, 64, 0, stream>>>(Xt, Xs, W1,b1,W2,b2,W3,b3,W4,b4,
                                   Wq,bq,Wk,bk,g_q,beta_q,g_k,beta_k,
                                   qf, kf, khi);
    k_scan<<<dim3(32,16,4), 256, 0, stream>>>(qf, khi, wsk);
    k_select<<<dim3(32,16), 256, 0, stream>>>(qf, kf, wsk, errors, y, y_pred, out, hacc);
    k_finalize<<<288, 256, 0, stream>>>(y, y_pred, errors, hacc, out);
}

// Round 9
// 753.988 us; speedup vs baseline: 1.0737x; 1.0737x over previous
//
#include <hip/hip_runtime.h>
#include <hip/hip_bf16.h>
#include <math.h>

// ConformHopfieldBatch: B=4 S=2048 IN=64 D=128 HID=400 H=4 K=20 NQ=18
// softmax monotone -> top_k(assoc) == top_k(raw scores). bf16-hi MFMA
// PREFILTER (A=K,B=Q swap; lane owns its q-row's scores in-register) ->
// approx candidates; exact fp32 RESCORE selects the true top-20 (R2 lesson).
// R8 postmortem: (a) 4 rows/wave doubled per-wave-count weight traffic
// (weight bytes/wave independent of rows/wave) -> revert to 8 rows/wave.
// (b) SPILL BUG FOUND: R5 counters show VGPR_Count=52 for the scan kernel
// vs ~90 demand -- __launch_bounds__(256) let the compiler cap VGPRs below
// keys[20] demand -> scratch spills on EVERY insert (~40 scratch ops/element)
// = the ~300us that survived 5 rewrites. Fix: __launch_bounds__(256,4)
// (cap 128 >= demand) on k_scan/k_select; (64,1) on k_mlp (~135 demand).

#define SS 2048

typedef short short8v __attribute__((ext_vector_type(8)));
typedef float float4v __attribute__((ext_vector_type(4)));

__constant__ float c_alphas[18] = {0.05f,0.06f,0.08f,0.1f,0.12f,0.14f,0.15f,0.17f,
                                   0.19f,0.2f,0.21f,0.23f,0.25f,0.3f,0.35f,0.38f,0.4f,0.45f};

// output flat offsets (return-order concat)
#define OFF_Y      1
#define OFF_YPRED  32769
#define OFF_YLOW   65537ll
#define OFF_YHIGH  655361ll
#define OFF_ERR    1245185ll
#define OFF_QLOW   1253377ll
#define OFF_QHIGH  1843201ll

__device__ inline short f2bf_s(float f) {
    __hip_bfloat16 h = __float2bfloat16(f);
    return __builtin_bit_cast(short, h);
}
// monotone fp32 -> u32 map (order-preserving)
__device__ inline unsigned mono(float f) {
    unsigned u = __builtin_bit_cast(unsigned, f);
    return (u & 0x80000000u) ? ~u : (u | 0x80000000u);
}
// wave-uniform register broadcast (v_readlane_b32)
__device__ inline float rdlane(float v, int l) {
    return __builtin_bit_cast(float, __builtin_amdgcn_readlane(__builtin_bit_cast(int, v), l));
}

// ---------------------------------------------------------------------------
// Kernel A: fused MLP + LayerNorm + projection. 64 threads, 8 rows/block.
// Activations register-resident: lane t holds cols {c*64+t} of every row;
// broadcast via readlane. No LDS. blocks 0..1023: true->q; 1024..2047: sim->k.
// launch_bounds(64,1): VGPR cap 512 >= ~135 demand -> no spills.
// ---------------------------------------------------------------------------
__global__ __launch_bounds__(64, 1) void k_mlp(
    const float* __restrict__ Xt, const float* __restrict__ Xs,
    const float* __restrict__ W1, const float* __restrict__ b1,
    const float* __restrict__ W2, const float* __restrict__ b2,
    const float* __restrict__ W3, const float* __restrict__ b3,
    const float* __restrict__ W4, const float* __restrict__ b4,
    const float* __restrict__ Wq, const float* __restrict__ bq,
    const float* __restrict__ Wk, const float* __restrict__ bk,
    const float* __restrict__ g_q, const float* __restrict__ beta_q,
    const float* __restrict__ g_k, const float* __restrict__ beta_k,
    float* __restrict__ qf, float* __restrict__ kf,
    __hip_bfloat16* __restrict__ khi)
{
    const int t    = threadIdx.x;          // 0..63
    const int bi   = blockIdx.x;
    const int half = bi >> 10;             // 0:true/q 1:sim/k
    const int rbase = (bi & 1023) * 8;     // row group within half
    const float* X = half ? Xs : Xt;

    int jm[7];                             // clamped col ids for 400-wide layers
    #pragma unroll
    for (int cc = 0; cc < 7; ++cc) { int j = cc*64 + t; jm[cc] = (j < 400) ? j : 399; }

    // input rows into registers: lane t holds x[r][t]
    float xreg[8];
    #pragma unroll
    for (int r = 0; r < 8; ++r) xreg[r] = X[(size_t)(rbase + r)*64 + t];

    float A1[8][7], A2[8][7];

    // ---- layer 1: 64 -> 400 (relu), xreg -> A1 ----
    {
        #pragma unroll
        for (int r = 0; r < 8; ++r)
            #pragma unroll
            for (int cc = 0; cc < 7; ++cc) A1[r][cc] = 0.f;
        #pragma unroll 4
        for (int il = 0; il < 64; ++il) {
            float wv[7];
            #pragma unroll
            for (int cc = 0; cc < 7; ++cc) wv[cc] = W1[il*400 + jm[cc]];
            #pragma unroll
            for (int r = 0; r < 8; ++r) {
                const float x = rdlane(xreg[r], il);
                #pragma unroll
                for (int cc = 0; cc < 7; ++cc) A1[r][cc] = fmaf(x, wv[cc], A1[r][cc]);
            }
        }
        #pragma unroll
        for (int cc = 0; cc < 7; ++cc) {
            const float bb = b1[jm[cc]];
            #pragma unroll
            for (int r = 0; r < 8; ++r) A1[r][cc] = fmaxf(A1[r][cc] + bb, 0.f);
        }
    }

    // ---- layer 2: 400 -> 400 (relu), A1 -> A2 ----
    {
        #pragma unroll
        for (int r = 0; r < 8; ++r)
            #pragma unroll
            for (int cc = 0; cc < 7; ++cc) A2[r][cc] = 0.f;
        #pragma unroll
        for (int cs = 0; cs < 7; ++cs) {
            const int ilim = (cs == 6) ? 16 : 64;
            #pragma unroll 4
            for (int il = 0; il < ilim; ++il) {
                const int i = cs*64 + il;
                float wv[7];
                #pragma unroll
                for (int cc = 0; cc < 7; ++cc) wv[cc] = W2[i*400 + jm[cc]];
                #pragma unroll
                for (int r = 0; r < 8; ++r) {
                    const float x = rdlane(A1[r][cs], il);
                    #pragma unroll
                    for (int cc = 0; cc < 7; ++cc) A2[r][cc] = fmaf(x, wv[cc], A2[r][cc]);
                }
            }
        }
        #pragma unroll
        for (int cc = 0; cc < 7; ++cc) {
            const float bb = b2[jm[cc]];
            #pragma unroll
            for (int r = 0; r < 8; ++r) A2[r][cc] = fmaxf(A2[r][cc] + bb, 0.f);
        }
    }

    // ---- layer 3: 400 -> 400 (relu), A2 -> A1 ----
    {
        #pragma unroll
        for (int r = 0; r < 8; ++r)
            #pragma unroll
            for (int cc = 0; cc < 7; ++cc) A1[r][cc] = 0.f;
        #pragma unroll
        for (int cs = 0; cs < 7; ++cs) {
            const int ilim = (cs == 6) ? 16 : 64;
            #pragma unroll 4
            for (int il = 0; il < ilim; ++il) {
                const int i = cs*64 + il;
                float wv[7];
                #pragma unroll
                for (int cc = 0; cc < 7; ++cc) wv[cc] = W3[i*400 + jm[cc]];
                #pragma unroll
                for (int r = 0; r < 8; ++r) {
                    const float x = rdlane(A2[r][cs], il);
                    #pragma unroll
                    for (int cc = 0; cc < 7; ++cc) A1[r][cc] = fmaf(x, wv[cc], A1[r][cc]);
                }
            }
        }
        #pragma unroll
        for (int cc = 0; cc < 7; ++cc) {
            const float bb = b3[jm[cc]];
            #pragma unroll
            for (int r = 0; r < 8; ++r) A1[r][cc] = fmaxf(A1[r][cc] + bb, 0.f);
        }
    }

    // ---- layer 4: 400 -> 128 (no relu), A1 -> acc4 (lane t: cols t, 64+t) ----
    float acc4[8][2];
    {
        #pragma unroll
        for (int r = 0; r < 8; ++r) { acc4[r][0] = 0.f; acc4[r][1] = 0.f; }
        #pragma unroll
        for (int cs = 0; cs < 7; ++cs) {
            const int ilim = (cs == 6) ? 16 : 64;
            #pragma unroll 4
            for (int il = 0; il < ilim; ++il) {
                const int i = cs*64 + il;
                const float w0 = W4[i*128 + t];
                const float w1 = W4[i*128 + 64 + t];
                #pragma unroll
                for (int r = 0; r < 8; ++r) {
                    const float x = rdlane(A1[r][cs], il);
                    acc4[r][0] = fmaf(x, w0, acc4[r][0]);
                    acc4[r][1] = fmaf(x, w1, acc4[r][1]);
                }
            }
        }
        const float bb0 = b4[t], bb1 = b4[64 + t];
        #pragma unroll
        for (int r = 0; r < 8; ++r) { acc4[r][0] += bb0; acc4[r][1] += bb1; }
    }

    // ---- LayerNorm over 128 (values spread: 2/lane x 64 lanes) ----
    float lnv[8][2];
    {
        const float* g  = half ? g_k : g_q;
        const float* be = half ? beta_k : beta_q;
        const float gl0 = g[t],  gl1 = g[64 + t];
        const float bl0 = be[t], bl1 = be[64 + t];
        #pragma unroll
        for (int r = 0; r < 8; ++r) {
            float s = acc4[r][0] + acc4[r][1];
            #pragma unroll
            for (int o = 32; o > 0; o >>= 1) s += __shfl_xor(s, o);
            const float mu = s * (1.f/128.f);
            const float d0 = acc4[r][0] - mu, d1 = acc4[r][1] - mu;
            float vs = d0*d0 + d1*d1;
            #pragma unroll
            for (int o = 32; o > 0; o >>= 1) vs += __shfl_xor(vs, o);
            const float rstd = rsqrtf(vs * (1.f/128.f) + 1e-5f);
            lnv[r][0] = d0*rstd*gl0 + bl0;
            lnv[r][1] = d1*rstd*gl1 + bl1;
        }
    }

    // ---- projection 128 -> 512 (8 cols/lane), write fp32 (+bf16-hi for k) ----
    {
        const float* Wp = half ? Wk : Wq;
        const float* bp = half ? bk : bq;
        float* of = half ? kf : qf;
        float accp[8][8];
        #pragma unroll
        for (int r = 0; r < 8; ++r)
            #pragma unroll
            for (int cc = 0; cc < 8; ++cc) accp[r][cc] = 0.f;
        #pragma unroll
        for (int cs = 0; cs < 2; ++cs) {
            #pragma unroll 4
            for (int il = 0; il < 64; ++il) {
                const int i = cs*64 + il;
                float wv[8];
                #pragma unroll
                for (int cc = 0; cc < 8; ++cc) wv[cc] = Wp[i*512 + cc*64 + t];
                #pragma unroll
                for (int r = 0; r < 8; ++r) {
                    const float x = rdlane(lnv[r][cs], il);
                    #pragma unroll
                    for (int cc = 0; cc < 8; ++cc) accp[r][cc] = fmaf(x, wv[cc], accp[r][cc]);
                }
            }
        }
        float bpv[8];
        #pragma unroll
        for (int cc = 0; cc < 8; ++cc) bpv[cc] = bp[cc*64 + t];
        #pragma unroll
        for (int r = 0; r < 8; ++r) {
            const int gidx = rbase + r;
            const int bb = gidx >> 11, s = gidx & 2047;
            #pragma unroll
            for (int cc = 0; cc < 8; ++cc) {
                const int j  = cc*64 + t;
                const int hh = j >> 7, d = j & 127;
                const float v = accp[r][cc] + bpv[cc];
                const size_t dst = ((size_t)(bb*4 + hh)*2048 + s)*128 + d;
                of[dst] = v;
                if (half) khi[dst] = __float2bfloat16(v);
            }
        }
    }
}

// ---------------------------------------------------------------------------
// Kernel B: MFMA scan over an m-quarter (512 cols) + branchless per-quad
// register top-20 + per-row owner merge -> approx-top-24 keys to ws.
// Block = (stile, hb, mq). launch_bounds(256,4): VGPR cap 128 >= ~90 demand
// -> keys[20] stays in registers (R8 spill-bug fix).
// ---------------------------------------------------------------------------
__global__ __launch_bounds__(256, 4) void k_scan(
    const float* __restrict__ qf, const __hip_bfloat16* __restrict__ khi,
    unsigned* __restrict__ wsk)
{
    __shared__ unsigned kd[64*4*21];   // 21.5KB lane-list dump (pad 21)

    const int tid   = threadIdx.x;
    const int stile = blockIdx.x;      // 0..31
    const int hb    = blockIdx.y;      // 0..15
    const int mq    = blockIdx.z;      // 0..3

    const int lane = tid & 63;
    const int w    = tid >> 6;
    const int m16  = lane & 15;
    const int quad = lane >> 4;

    const size_t slab = (size_t)hb * 2048;
    const __hip_bfloat16* slabp = khi + slab*128;

    const int sg_my = stile*64 + w*16 + m16;

    // Q fragment (B operand): B[n=m16][k=quad*8+j+ks*32] = q[w*16+n][k]
    short8v bq_[4];
    {
        const float* qp = qf + (slab + sg_my)*128 + quad*8;
        #pragma unroll
        for (int ks = 0; ks < 4; ++ks) {
            const float4 x0 = *(const float4*)(qp + ks*32);
            const float4 x1 = *(const float4*)(qp + ks*32 + 4);
            short8v tt;
            tt[0]=f2bf_s(x0.x); tt[1]=f2bf_s(x0.y); tt[2]=f2bf_s(x0.z); tt[3]=f2bf_s(x0.w);
            tt[4]=f2bf_s(x1.x); tt[5]=f2bf_s(x1.y); tt[6]=f2bf_s(x1.z); tt[7]=f2bf_s(x1.w);
            bq_[ks] = tt;
        }
    }

    unsigned keys[20];                 // ascending; keys[0] = min
    #pragma unroll
    for (int n = 0; n < 20; ++n) keys[n] = 0u;

    #pragma unroll 1
    for (int cti = 0; cti < 32; ++cti) {
        const int colb = mq*512 + cti*16;
        const __hip_bfloat16* kp = slabp + (size_t)(colb + m16)*128 + quad*8;
        float4v acc = (float4v){0.f,0.f,0.f,0.f};
        #pragma unroll
        for (int ks = 0; ks < 4; ++ks) {
            const short8v ka = *(const short8v*)(kp + ks*32);
            acc = __builtin_amdgcn_mfma_f32_16x16x32_bf16(ka, bq_[ks], acc, 0, 0, 0);
        }
        const int cb = colb + quad*4;
        #pragma unroll
        for (int reg = 0; reg < 4; ++reg) {
            const int m = cb + reg;
            unsigned key = (mono(acc[reg]) & 0xFFFFF800u) | (unsigned)m;
            key = (m == sg_my) ? 0u : key;              // diagonal excluded
            keys[0] = (key > keys[0]) ? key : keys[0];  // drop-min insert
            #pragma unroll
            for (int i = 0; i < 19; ++i) {              // bubble restores order
                const unsigned a = keys[i], c = keys[i+1];
                keys[i]   = (a < c) ? a : c;
                keys[i+1] = (a < c) ? c : a;
            }
        }
    }

    // dump descending per (row, quad)
    const int rr = w*16 + m16;
    #pragma unroll
    for (int n = 0; n < 20; ++n)
        kd[(rr*4 + quad)*21 + n] = keys[19 - n];
    __syncthreads();

    // owner (quad 0): merge 4 sorted-desc 20-lists -> top-24 -> ws (desc)
    if (quad == 0) {
        const unsigned* L0 = &kd[(rr*4 + 0)*21];
        const unsigned* L1 = &kd[(rr*4 + 1)*21];
        const unsigned* L2 = &kd[(rr*4 + 2)*21];
        const unsigned* L3 = &kd[(rr*4 + 3)*21];
        int p0 = 0, p1 = 0, p2 = 0, p3 = 0;
        const size_t base = (size_t)hb*2048 + stile*64 + rr;
        #pragma unroll 1
        for (int n = 0; n < 24; ++n) {
            const unsigned h0 = (p0 < 20) ? L0[p0] : 0u;
            const unsigned h1 = (p1 < 20) ? L1[p1] : 0u;
            const unsigned h2 = (p2 < 20) ? L2[p2] : 0u;
            const unsigned h3 = (p3 < 20) ? L3[p3] : 0u;
            unsigned bv = h0; int bs = 0;
            if (h1 > bv) { bv = h1; bs = 1; }
            if (h2 > bv) { bv = h2; bs = 2; }
            if (h3 > bv) { bv = h3; bs = 3; }
            if (bs == 0) ++p0; else if (bs == 1) ++p1; else if (bs == 2) ++p2; else ++p3;
            wsk[(size_t)(mq*24 + n)*32768 + base] = bv;
        }
    }
}

// ---------------------------------------------------------------------------
// Kernel C: per row merge 4x24 approx keys -> top-32 -> cooperative exact
// fp32 rescore (4 lanes/row, coalesced segments, butterfly reduce) -> exact
// top-20 -> quantiles + outputs + score accumulation.
// Block = (stile, hb), 64 rows. launch_bounds(256,4): no spills.
// ---------------------------------------------------------------------------
__global__ __launch_bounds__(256, 4) void k_select(
    const float* __restrict__ qf, const float* __restrict__ kf,
    const unsigned* __restrict__ wsk,
    const float* __restrict__ errors, const float* __restrict__ y,
    const float* __restrict__ y_pred,
    float* __restrict__ out, float* __restrict__ hacc)
{
    __shared__ unsigned kd[64*4*25];       // 25.6KB (pad 25)
    __shared__ unsigned short cb[64*33];   // 4.2KB candidate cols
    __shared__ float es[64*33];            // 8.4KB exact scores
    __shared__ float ebuf[64*21];          // 5.4KB sort buffer

    const int tid   = threadIdx.x;
    const int stile = blockIdx.x;          // 0..31
    const int hb    = blockIdx.y;          // 0..15
    const int b     = hb >> 2;
    const int h     = hb & 3;

    const int lane = tid & 63;
    const int w    = tid >> 6;
    const int m16  = lane & 15;
    const int quad = lane >> 4;
    const int rr   = w*16 + m16;
    const int sg   = stile*64 + rr;

    const size_t base = (size_t)hb*2048 + sg;
    // lane loads mq=quad's 24 keys (coalesced across rows)
    #pragma unroll 1
    for (int n = 0; n < 24; ++n)
        kd[(rr*4 + quad)*25 + n] = wsk[(size_t)(quad*24 + n)*32768 + base];
    __syncthreads();

    // owner: merge 4 sorted-desc 24-lists -> approx-top-32 cols
    if (quad == 0) {
        const unsigned* L0 = &kd[(rr*4 + 0)*25];
        const unsigned* L1 = &kd[(rr*4 + 1)*25];
        const unsigned* L2 = &kd[(rr*4 + 2)*25];
        const unsigned* L3 = &kd[(rr*4 + 3)*25];
        int p0 = 0, p1 = 0, p2 = 0, p3 = 0;
        #pragma unroll 1
        for (int n = 0; n < 32; ++n) {
            const unsigned h0 = (p0 < 24) ? L0[p0] : 0u;
            const unsigned h1 = (p1 < 24) ? L1[p1] : 0u;
            const unsigned h2 = (p2 < 24) ? L2[p2] : 0u;
            const unsigned h3 = (p3 < 24) ? L3[p3] : 0u;
            unsigned bv = h0; int bs = 0;
            if (h1 > bv) { bv = h1; bs = 1; }
            if (h2 > bv) { bv = h2; bs = 2; }
            if (h3 > bv) { bv = h3; bs = 3; }
            if (bs == 0) ++p0; else if (bs == 1) ++p1; else if (bs == 2) ++p2; else ++p3;
            cb[rr*33 + n] = (unsigned short)(bv & 0x7FFu);
        }
    }
    __syncthreads();

    // cooperative exact rescore of the 32 candidates
    const size_t slab = (size_t)hb * 2048;
    const float* qrow_p = qf + (slab + sg)*128;
    float4 qseg[8];
    #pragma unroll
    for (int u = 0; u < 8; ++u)
        qseg[u] = *(const float4*)(qrow_p + quad*4 + u*16);
    const float* kslab = kf + slab*128;
    #pragma unroll 1
    for (int n = 0; n < 32; ++n) {
        const int col = cb[rr*33 + n];
        const float* kc = kslab + (size_t)col*128 + quad*4;
        float4v s = (float4v){0.f,0.f,0.f,0.f};
        #pragma unroll
        for (int u = 0; u < 8; ++u) {
            const float4 kv = *(const float4*)(kc + u*16);
            s[0] = fmaf(qseg[u].x, kv.x, s[0]);
            s[1] = fmaf(qseg[u].y, kv.y, s[1]);
            s[2] = fmaf(qseg[u].z, kv.z, s[2]);
            s[3] = fmaf(qseg[u].w, kv.w, s[3]);
        }
        float v = (s[0] + s[1]) + (s[2] + s[3]);
        v += __shfl_xor(v, 16);
        v += __shfl_xor(v, 32);
        if (quad == 0) es[rr*33 + n] = v;
    }

    // owner: exact top-20 selection (desc, col asc ties) + quantiles
    float sq = 0.f;
    if (quad == 0) {
        float* e = &ebuf[rr*21];
        #pragma unroll 1
        for (int k = 0; k < 20; ++k) {
            float best = -INFINITY; int bc = 4096, bj = 0;
            #pragma unroll 1
            for (int j = 0; j < 32; ++j) {
                const float v = es[rr*33 + j];
                const int c = cb[rr*33 + j];
                if (v > best || (v == best && c < bc)) { best = v; bc = c; bj = j; }
            }
            es[rr*33 + bj] = -INFINITY;
            e[k] = errors[((size_t)(b*SS + bc))*4];   // errors[..., 0]
        }
        #pragma unroll 1
        for (int a = 1; a < 20; ++a) {     // insertion sort ascending
            const float v = e[a];
            int n = a;
            while (n > 0 && e[n-1] > v) { e[n] = e[n-1]; --n; }
            e[n] = v;
        }
        const float yp = y_pred[((size_t)(b*SS + sg))*4];
        const float yt = y[((size_t)(b*SS + sg))*4];
        float msum = 0.f;
        const size_t obase = ((size_t)(h*4 + b)*18)*2048 + sg;
        #pragma unroll 1
        for (int a = 0; a < 18; ++a) {
            const float alpha = c_alphas[a];
            const float beta  = 0.5f*alpha;
            const float pl = beta * 19.f;
            const int   il = (int)pl;
            const float fl = pl - (float)il;
            const float ql = e[il]*(1.f-fl) + e[il+1]*fl;
            const float qq = (1.f - alpha) + beta;
            const float ph = qq * 19.f;
            const int   ih = (int)ph;
            const float fh = ph - (float)ih;
            const float qh = e[ih]*(1.f-fh) + e[ih+1]*fh;
            msum += ql + qh;
            const size_t oidx = obase + (size_t)a*2048;
            out[OFF_YLOW  + oidx] = ql + yp;
            out[OFF_YHIGH + oidx] = qh + yp;
            out[OFF_QLOW  + oidx] = ql;
            out[OFF_QHIGH + oidx] = qh;
        }
        const float me = msum * (1.f/36.f);
        const float dd = yt - (me + yp);
        sq = dd*dd;
    }
    // wave-reduce sq (non-owners contribute 0), one atomic per wave
    #pragma unroll
    for (int o = 32; o > 0; o >>= 1) sq += __shfl_xor(sq, o);
    if (lane == 0) atomicAdd(&hacc[h], sq);
}

__global__ void k_init(float* __restrict__ hacc) {
    if (threadIdx.x < 4) hacc[threadIdx.x] = 0.f;
}

__global__ __launch_bounds__(256) void k_finalize(
    const float* __restrict__ y, const float* __restrict__ y_pred,
    const float* __restrict__ errors, const float* __restrict__ hacc,
    float* __restrict__ out)
{
    const int i = blockIdx.x*256 + threadIdx.x;
    if (i == 0)
        out[0] = (hacc[0]+hacc[1]+hacc[2]+hacc[3]) * (1.f/32768.f);
    if (i < 32768)      out[OFF_Y + i] = y[i];
    else if (i < 65536) out[OFF_YPRED + (i - 32768)] = y_pred[i - 32768];
    else if (i < 73728) { const int j = i - 65536; out[OFF_ERR + j] = errors[(size_t)j*4]; }
}

extern "C" void kernel_launch(void* const* d_in, const int* in_sizes, int n_in,
                              void* d_out, int out_size, void* d_ws, size_t ws_size,
                              hipStream_t stream)
{
    const float* Xt     = (const float*)d_in[0];
    const float* Xs     = (const float*)d_in[1];
    const float* errors = (const float*)d_in[2];
    const float* y      = (const float*)d_in[3];
    const float* y_pred = (const float*)d_in[4];
    const float* W1 = (const float*)d_in[5];   const float* b1 = (const float*)d_in[6];
    const float* W2 = (const float*)d_in[7];   const float* b2 = (const float*)d_in[8];
    const float* W3 = (const float*)d_in[9];   const float* b3 = (const float*)d_in[10];
    const float* W4 = (const float*)d_in[11];  const float* b4 = (const float*)d_in[12];
    const float* Wq = (const float*)d_in[13];  const float* bq = (const float*)d_in[14];
    const float* Wk = (const float*)d_in[15];  const float* bk = (const float*)d_in[16];
    const float* g_q    = (const float*)d_in[17];
    const float* beta_q = (const float*)d_in[18];
    const float* g_k    = (const float*)d_in[19];
    const float* beta_k = (const float*)d_in[20];

    float* out  = (float*)d_out;
    char*  base = (char*)d_ws;
    const size_t SLAB = (size_t)16*2048*128;               // 4,194,304 elements
    float* hacc = (float*)base;                            // 64B slot
    float* qf   = (float*)(base + 256);                    // 16MB
    float* kf   = qf + SLAB;                               // 16MB
    __hip_bfloat16* khi = (__hip_bfloat16*)(kf + SLAB);    // 8MB
    unsigned* wsk = (unsigned*)(khi + SLAB);               // 4*24*32768 u32 = 12.6MB

    k_init<<<1, 64, 0, stream>>>(hacc);
    k_mlp<<<2048, 64, 0, stream>>>(Xt, Xs, W1,b1,W2,b2,W3,b3,W4,b4,
                                   Wq,bq,Wk,bk,g_q,beta_q,g_k,beta_k,
                                   qf, kf, khi);
    k_scan<<<dim3(32,16,4), 256, 0, stream>>>(qf, khi, wsk);
    k_select<<<dim3(32,16), 256, 0, stream>>>(qf, kf, wsk, errors, y, y_pred, out, hacc);
    k_finalize<<<288, 256, 0, stream>>>(y, y_pred, errors, hacc, out);
}

// Round 10
// 714.169 us; speedup vs baseline: 1.1335x; 1.0558x over previous
//
#include <hip/hip_runtime.h>
#include <hip/hip_bf16.h>
#include <math.h>

// ConformHopfieldBatch: B=4 S=2048 IN=64 D=128 HID=400 H=4 K=20 NQ=18
// softmax monotone -> top_k(assoc) == top_k(raw scores). bf16-hi MFMA
// PREFILTER -> approx candidates; exact fp32 RESCORE -> true top-20 (R2).
// R9 postmortem: scan+select pinned at ~360us across 4 structurally
// different versions (R6 fused / R7 unrolled / R8 rolled / R9 launch-bounds)
// while VALU models say ~100us -> the invariant is the K-frag LOAD SCATTER:
// lanes m16 read rows 256B apart => every dwordx4 touches 16 cache lines.
// R10: khi stored PRE-SWIZZLED in MFMA-A-fragment order by k_mlp; the scan's
// 4 loads/cti each read a contiguous 1KB across the wave (ideal pattern).
// Layout: elem(s,d) -> slab*262144 + (s>>4)*2048 + (d>>5)*512
//                      + ((d&31)>>3)*128 + (s&15)*8 + (d&7).
// Zero numeric change; only khi addressing. kf/qf paths untouched.

#define SS 2048

typedef short short8v __attribute__((ext_vector_type(8)));
typedef float float4v __attribute__((ext_vector_type(4)));

__constant__ float c_alphas[18] = {0.05f,0.06f,0.08f,0.1f,0.12f,0.14f,0.15f,0.17f,
                                   0.19f,0.2f,0.21f,0.23f,0.25f,0.3f,0.35f,0.38f,0.4f,0.45f};

// output flat offsets (return-order concat)
#define OFF_Y      1
#define OFF_YPRED  32769
#define OFF_YLOW   65537ll
#define OFF_YHIGH  655361ll
#define OFF_ERR    1245185ll
#define OFF_QLOW   1253377ll
#define OFF_QHIGH  1843201ll

__device__ inline short f2bf_s(float f) {
    __hip_bfloat16 h = __float2bfloat16(f);
    return __builtin_bit_cast(short, h);
}
// monotone fp32 -> u32 map (order-preserving)
__device__ inline unsigned mono(float f) {
    unsigned u = __builtin_bit_cast(unsigned, f);
    return (u & 0x80000000u) ? ~u : (u | 0x80000000u);
}
// wave-uniform register broadcast (v_readlane_b32)
__device__ inline float rdlane(float v, int l) {
    return __builtin_bit_cast(float, __builtin_amdgcn_readlane(__builtin_bit_cast(int, v), l));
}
__device__ inline unsigned umin_(unsigned a, unsigned b) { return a < b ? a : b; }
__device__ inline unsigned umax_(unsigned a, unsigned b) { return a > b ? a : b; }

// ---------------------------------------------------------------------------
// Kernel A: fused MLP + LayerNorm + projection. 64 threads, 8 rows/block.
// Activations register-resident; readlane broadcast; no LDS.
// blocks 0..1023: true->q; 1024..2047: sim->k (fp32 + SWIZZLED bf16-hi).
// ---------------------------------------------------------------------------
__global__ __launch_bounds__(64, 1) void k_mlp(
    const float* __restrict__ Xt, const float* __restrict__ Xs,
    const float* __restrict__ W1, const float* __restrict__ b1,
    const float* __restrict__ W2, const float* __restrict__ b2,
    const float* __restrict__ W3, const float* __restrict__ b3,
    const float* __restrict__ W4, const float* __restrict__ b4,
    const float* __restrict__ Wq, const float* __restrict__ bq,
    const float* __restrict__ Wk, const float* __restrict__ bk,
    const float* __restrict__ g_q, const float* __restrict__ beta_q,
    const float* __restrict__ g_k, const float* __restrict__ beta_k,
    float* __restrict__ qf, float* __restrict__ kf,
    __hip_bfloat16* __restrict__ khi)
{
    const int t    = threadIdx.x;          // 0..63
    const int bi   = blockIdx.x;
    const int half = bi >> 10;             // 0:true/q 1:sim/k
    const int rbase = (bi & 1023) * 8;     // row group within half
    const float* X = half ? Xs : Xt;

    int jm[7];                             // clamped col ids for 400-wide layers
    #pragma unroll
    for (int cc = 0; cc < 7; ++cc) { int j = cc*64 + t; jm[cc] = (j < 400) ? j : 399; }

    // input rows into registers: lane t holds x[r][t]
    float xreg[8];
    #pragma unroll
    for (int r = 0; r < 8; ++r) xreg[r] = X[(size_t)(rbase + r)*64 + t];

    float A1[8][7], A2[8][7];

    // ---- layer 1: 64 -> 400 (relu), xreg -> A1 ----
    {
        #pragma unroll
        for (int r = 0; r < 8; ++r)
            #pragma unroll
            for (int cc = 0; cc < 7; ++cc) A1[r][cc] = 0.f;
        #pragma unroll 4
        for (int il = 0; il < 64; ++il) {
            float wv[7];
            #pragma unroll
            for (int cc = 0; cc < 7; ++cc) wv[cc] = W1[il*400 + jm[cc]];
            #pragma unroll
            for (int r = 0; r < 8; ++r) {
                const float x = rdlane(xreg[r], il);
                #pragma unroll
                for (int cc = 0; cc < 7; ++cc) A1[r][cc] = fmaf(x, wv[cc], A1[r][cc]);
            }
        }
        #pragma unroll
        for (int cc = 0; cc < 7; ++cc) {
            const float bb = b1[jm[cc]];
            #pragma unroll
            for (int r = 0; r < 8; ++r) A1[r][cc] = fmaxf(A1[r][cc] + bb, 0.f);
        }
    }

    // ---- layer 2: 400 -> 400 (relu), A1 -> A2 ----
    {
        #pragma unroll
        for (int r = 0; r < 8; ++r)
            #pragma unroll
            for (int cc = 0; cc < 7; ++cc) A2[r][cc] = 0.f;
        #pragma unroll
        for (int cs = 0; cs < 7; ++cs) {
            const int ilim = (cs == 6) ? 16 : 64;
            #pragma unroll 4
            for (int il = 0; il < ilim; ++il) {
                const int i = cs*64 + il;
                float wv[7];
                #pragma unroll
                for (int cc = 0; cc < 7; ++cc) wv[cc] = W2[i*400 + jm[cc]];
                #pragma unroll
                for (int r = 0; r < 8; ++r) {
                    const float x = rdlane(A1[r][cs], il);
                    #pragma unroll
                    for (int cc = 0; cc < 7; ++cc) A2[r][cc] = fmaf(x, wv[cc], A2[r][cc]);
                }
            }
        }
        #pragma unroll
        for (int cc = 0; cc < 7; ++cc) {
            const float bb = b2[jm[cc]];
            #pragma unroll
            for (int r = 0; r < 8; ++r) A2[r][cc] = fmaxf(A2[r][cc] + bb, 0.f);
        }
    }

    // ---- layer 3: 400 -> 400 (relu), A2 -> A1 ----
    {
        #pragma unroll
        for (int r = 0; r < 8; ++r)
            #pragma unroll
            for (int cc = 0; cc < 7; ++cc) A1[r][cc] = 0.f;
        #pragma unroll
        for (int cs = 0; cs < 7; ++cs) {
            const int ilim = (cs == 6) ? 16 : 64;
            #pragma unroll 4
            for (int il = 0; il < ilim; ++il) {
                const int i = cs*64 + il;
                float wv[7];
                #pragma unroll
                for (int cc = 0; cc < 7; ++cc) wv[cc] = W3[i*400 + jm[cc]];
                #pragma unroll
                for (int r = 0; r < 8; ++r) {
                    const float x = rdlane(A2[r][cs], il);
                    #pragma unroll
                    for (int cc = 0; cc < 7; ++cc) A1[r][cc] = fmaf(x, wv[cc], A1[r][cc]);
                }
            }
        }
        #pragma unroll
        for (int cc = 0; cc < 7; ++cc) {
            const float bb = b3[jm[cc]];
            #pragma unroll
            for (int r = 0; r < 8; ++r) A1[r][cc] = fmaxf(A1[r][cc] + bb, 0.f);
        }
    }

    // ---- layer 4: 400 -> 128 (no relu), A1 -> acc4 (lane t: cols t, 64+t) ----
    float acc4[8][2];
    {
        #pragma unroll
        for (int r = 0; r < 8; ++r) { acc4[r][0] = 0.f; acc4[r][1] = 0.f; }
        #pragma unroll
        for (int cs = 0; cs < 7; ++cs) {
            const int ilim = (cs == 6) ? 16 : 64;
            #pragma unroll 4
            for (int il = 0; il < ilim; ++il) {
                const int i = cs*64 + il;
                const float w0 = W4[i*128 + t];
                const float w1 = W4[i*128 + 64 + t];
                #pragma unroll
                for (int r = 0; r < 8; ++r) {
                    const float x = rdlane(A1[r][cs], il);
                    acc4[r][0] = fmaf(x, w0, acc4[r][0]);
                    acc4[r][1] = fmaf(x, w1, acc4[r][1]);
                }
            }
        }
        const float bb0 = b4[t], bb1 = b4[64 + t];
        #pragma unroll
        for (int r = 0; r < 8; ++r) { acc4[r][0] += bb0; acc4[r][1] += bb1; }
    }

    // ---- LayerNorm over 128 (values spread: 2/lane x 64 lanes) ----
    float lnv[8][2];
    {
        const float* g  = half ? g_k : g_q;
        const float* be = half ? beta_k : beta_q;
        const float gl0 = g[t],  gl1 = g[64 + t];
        const float bl0 = be[t], bl1 = be[64 + t];
        #pragma unroll
        for (int r = 0; r < 8; ++r) {
            float s = acc4[r][0] + acc4[r][1];
            #pragma unroll
            for (int o = 32; o > 0; o >>= 1) s += __shfl_xor(s, o);
            const float mu = s * (1.f/128.f);
            const float d0 = acc4[r][0] - mu, d1 = acc4[r][1] - mu;
            float vs = d0*d0 + d1*d1;
            #pragma unroll
            for (int o = 32; o > 0; o >>= 1) vs += __shfl_xor(vs, o);
            const float rstd = rsqrtf(vs * (1.f/128.f) + 1e-5f);
            lnv[r][0] = d0*rstd*gl0 + bl0;
            lnv[r][1] = d1*rstd*gl1 + bl1;
        }
    }

    // ---- projection 128 -> 512 (8 cols/lane), write fp32 (+swizzled bf16) ----
    {
        const float* Wp = half ? Wk : Wq;
        const float* bp = half ? bk : bq;
        float* of = half ? kf : qf;
        float accp[8][8];
        #pragma unroll
        for (int r = 0; r < 8; ++r)
            #pragma unroll
            for (int cc = 0; cc < 8; ++cc) accp[r][cc] = 0.f;
        #pragma unroll
        for (int cs = 0; cs < 2; ++cs) {
            #pragma unroll 4
            for (int il = 0; il < 64; ++il) {
                const int i = cs*64 + il;
                float wv[8];
                #pragma unroll
                for (int cc = 0; cc < 8; ++cc) wv[cc] = Wp[i*512 + cc*64 + t];
                #pragma unroll
                for (int r = 0; r < 8; ++r) {
                    const float x = rdlane(lnv[r][cs], il);
                    #pragma unroll
                    for (int cc = 0; cc < 8; ++cc) accp[r][cc] = fmaf(x, wv[cc], accp[r][cc]);
                }
            }
        }
        float bpv[8];
        #pragma unroll
        for (int cc = 0; cc < 8; ++cc) bpv[cc] = bp[cc*64 + t];
        #pragma unroll
        for (int r = 0; r < 8; ++r) {
            const int gidx = rbase + r;
            const int bb = gidx >> 11, s = gidx & 2047;
            const int T = s >> 4, m16s = s & 15;
            #pragma unroll
            for (int cc = 0; cc < 8; ++cc) {
                const int j  = cc*64 + t;
                const int hh = j >> 7, d = j & 127;
                const float v = accp[r][cc] + bpv[cc];
                const size_t dst = ((size_t)(bb*4 + hh)*2048 + s)*128 + d;
                of[dst] = v;
                if (half) {
                    // MFMA-A-fragment swizzle: lane (quad=(d&31)>>3? no -
                    // quad_d from dim, m16 from s)
                    const int ks = d >> 5, qd = (d & 31) >> 3, jj = d & 7;
                    const size_t so = (size_t)(bb*4 + hh)*262144
                                    + (size_t)T*2048 + ks*512 + qd*128 + m16s*8 + jj;
                    khi[so] = __float2bfloat16(v);
                }
            }
        }
    }
}

// ---------------------------------------------------------------------------
// Kernel B: MFMA scan over an m-quarter (512 cols) + branchless per-quad
// register top-20 + per-row owner merge -> approx-top-24 keys to ws.
// khi is in fragment order: per cti each of the 4 ks-loads reads a fully
// contiguous 1KB across the wave (lane*8 + ks*512 within tile).
// ---------------------------------------------------------------------------
__global__ __launch_bounds__(256, 4) void k_scan(
    const float* __restrict__ qf, const __hip_bfloat16* __restrict__ khi,
    unsigned* __restrict__ wsk)
{
    __shared__ unsigned kd[64*4*21];   // 21.5KB lane-list dump (pad 21)

    const int tid   = threadIdx.x;
    const int stile = blockIdx.x;      // 0..31
    const int hb    = blockIdx.y;      // 0..15
    const int mq    = blockIdx.z;      // 0..3

    const int lane = tid & 63;
    const int w    = tid >> 6;
    const int m16  = lane & 15;
    const int quad = lane >> 4;

    const size_t slab = (size_t)hb * 2048;
    const __hip_bfloat16* slabp = khi + (size_t)hb * 262144;   // swizzled slab

    const int sg_my = stile*64 + w*16 + m16;

    // Q fragment (B operand): B[n=m16][k=quad*8+j+ks*32] = q[w*16+n][k]
    short8v bq_[4];
    {
        const float* qp = qf + (slab + sg_my)*128 + quad*8;
        #pragma unroll
        for (int ks = 0; ks < 4; ++ks) {
            const float4 x0 = *(const float4*)(qp + ks*32);
            const float4 x1 = *(const float4*)(qp + ks*32 + 4);
            short8v tt;
            tt[0]=f2bf_s(x0.x); tt[1]=f2bf_s(x0.y); tt[2]=f2bf_s(x0.z); tt[3]=f2bf_s(x0.w);
            tt[4]=f2bf_s(x1.x); tt[5]=f2bf_s(x1.y); tt[6]=f2bf_s(x1.z); tt[7]=f2bf_s(x1.w);
            bq_[ks] = tt;
        }
    }

    unsigned keys[20];                 // ascending; keys[0] = min
    #pragma unroll
    for (int n = 0; n < 20; ++n) keys[n] = 0u;

    #pragma unroll 1
    for (int cti = 0; cti < 32; ++cti) {
        const int T = mq*32 + cti;     // global 16-col tile id
        const __hip_bfloat16* kp = slabp + (size_t)T*2048 + lane*8;
        float4v acc = (float4v){0.f,0.f,0.f,0.f};
        #pragma unroll
        for (int ks = 0; ks < 4; ++ks) {
            const short8v ka = *(const short8v*)(kp + ks*512);
            acc = __builtin_amdgcn_mfma_f32_16x16x32_bf16(ka, bq_[ks], acc, 0, 0, 0);
        }
        const int cb = T*16 + quad*4;
        #pragma unroll
        for (int reg = 0; reg < 4; ++reg) {
            const int m = cb + reg;
            unsigned key = (mono(acc[reg]) & 0xFFFFF800u) | (unsigned)m;
            key = (m == sg_my) ? 0u : key;              // diagonal excluded
            keys[0] = umax_(keys[0], key);              // drop-min insert
            #pragma unroll
            for (int i = 0; i < 19; ++i) {              // bubble restores order
                const unsigned a = keys[i], c = keys[i+1];
                keys[i]   = umin_(a, c);
                keys[i+1] = umax_(a, c);
            }
        }
    }

    // dump descending per (row, quad)
    const int rr = w*16 + m16;
    #pragma unroll
    for (int n = 0; n < 20; ++n)
        kd[(rr*4 + quad)*21 + n] = keys[19 - n];
    __syncthreads();

    // owner (quad 0): merge 4 sorted-desc 20-lists -> top-24 -> ws (desc)
    if (quad == 0) {
        const unsigned* L0 = &kd[(rr*4 + 0)*21];
        const unsigned* L1 = &kd[(rr*4 + 1)*21];
        const unsigned* L2 = &kd[(rr*4 + 2)*21];
        const unsigned* L3 = &kd[(rr*4 + 3)*21];
        int p0 = 0, p1 = 0, p2 = 0, p3 = 0;
        const size_t base = (size_t)hb*2048 + stile*64 + rr;
        #pragma unroll 1
        for (int n = 0; n < 24; ++n) {
            const unsigned h0 = (p0 < 20) ? L0[p0] : 0u;
            const unsigned h1 = (p1 < 20) ? L1[p1] : 0u;
            const unsigned h2 = (p2 < 20) ? L2[p2] : 0u;
            const unsigned h3 = (p3 < 20) ? L3[p3] : 0u;
            unsigned bv = h0; int bs = 0;
            if (h1 > bv) { bv = h1; bs = 1; }
            if (h2 > bv) { bv = h2; bs = 2; }
            if (h3 > bv) { bv = h3; bs = 3; }
            if (bs == 0) ++p0; else if (bs == 1) ++p1; else if (bs == 2) ++p2; else ++p3;
            wsk[(size_t)(mq*24 + n)*32768 + base] = bv;
        }
    }
}

// ---------------------------------------------------------------------------
// Kernel C: per row merge 4x24 approx keys -> top-32 -> cooperative exact
// fp32 rescore -> exact top-20 -> quantiles + outputs + score accumulation.
// ---------------------------------------------------------------------------
__global__ __launch_bounds__(256, 4) void k_select(
    const float* __restrict__ qf, const float* __restrict__ kf,
    const unsigned* __restrict__ wsk,
    const float* __restrict__ errors, const float* __restrict__ y,
    const float* __restrict__ y_pred,
    float* __restrict__ out, float* __restrict__ hacc)
{
    __shared__ unsigned kd[64*4*25];       // 25.6KB (pad 25)
    __shared__ unsigned short cb[64*33];   // 4.2KB candidate cols
    __shared__ float es[64*33];            // 8.4KB exact scores
    __shared__ float ebuf[64*21];          // 5.4KB sort buffer

    const int tid   = threadIdx.x;
    const int stile = blockIdx.x;          // 0..31
    const int hb    = blockIdx.y;          // 0..15
    const int b     = hb >> 2;
    const int h     = hb & 3;

    const int lane = tid & 63;
    const int w    = tid >> 6;
    const int m16  = lane & 15;
    const int quad = lane >> 4;
    const int rr   = w*16 + m16;
    const int sg   = stile*64 + rr;

    const size_t base = (size_t)hb*2048 + sg;
    // lane loads mq=quad's 24 keys (coalesced across rows)
    #pragma unroll 1
    for (int n = 0; n < 24; ++n)
        kd[(rr*4 + quad)*25 + n] = wsk[(size_t)(quad*24 + n)*32768 + base];
    __syncthreads();

    // owner: merge 4 sorted-desc 24-lists -> approx-top-32 cols
    if (quad == 0) {
        const unsigned* L0 = &kd[(rr*4 + 0)*25];
        const unsigned* L1 = &kd[(rr*4 + 1)*25];
        const unsigned* L2 = &kd[(rr*4 + 2)*25];
        const unsigned* L3 = &kd[(rr*4 + 3)*25];
        int p0 = 0, p1 = 0, p2 = 0, p3 = 0;
        #pragma unroll 1
        for (int n = 0; n < 32; ++n) {
            const unsigned h0 = (p0 < 24) ? L0[p0] : 0u;
            const unsigned h1 = (p1 < 24) ? L1[p1] : 0u;
            const unsigned h2 = (p2 < 24) ? L2[p2] : 0u;
            const unsigned h3 = (p3 < 24) ? L3[p3] : 0u;
            unsigned bv = h0; int bs = 0;
            if (h1 > bv) { bv = h1; bs = 1; }
            if (h2 > bv) { bv = h2; bs = 2; }
            if (h3 > bv) { bv = h3; bs = 3; }
            if (bs == 0) ++p0; else if (bs == 1) ++p1; else if (bs == 2) ++p2; else ++p3;
            cb[rr*33 + n] = (unsigned short)(bv & 0x7FFu);
        }
    }
    __syncthreads();

    // cooperative exact rescore of the 32 candidates
    const size_t slab = (size_t)hb * 2048;
    const float* qrow_p = qf + (slab + sg)*128;
    float4 qseg[8];
    #pragma unroll
    for (int u = 0; u < 8; ++u)
        qseg[u] = *(const float4*)(qrow_p + quad*4 + u*16);
    const float* kslab = kf + slab*128;
    #pragma unroll 1
    for (int n = 0; n < 32; ++n) {
        const int col = cb[rr*33 + n];
        const float* kc = kslab + (size_t)col*128 + quad*4;
        float4v s = (float4v){0.f,0.f,0.f,0.f};
        #pragma unroll
        for (int u = 0; u < 8; ++u) {
            const float4 kv = *(const float4*)(kc + u*16);
            s[0] = fmaf(qseg[u].x, kv.x, s[0]);
            s[1] = fmaf(qseg[u].y, kv.y, s[1]);
            s[2] = fmaf(qseg[u].z, kv.z, s[2]);
            s[3] = fmaf(qseg[u].w, kv.w, s[3]);
        }
        float v = (s[0] + s[1]) + (s[2] + s[3]);
        v += __shfl_xor(v, 16);
        v += __shfl_xor(v, 32);
        if (quad == 0) es[rr*33 + n] = v;
    }

    // owner: exact top-20 selection (desc, col asc ties) + quantiles
    float sq = 0.f;
    if (quad == 0) {
        float* e = &ebuf[rr*21];
        #pragma unroll 1
        for (int k = 0; k < 20; ++k) {
            float best = -INFINITY; int bc = 4096, bj = 0;
            #pragma unroll 1
            for (int j = 0; j < 32; ++j) {
                const float v = es[rr*33 + j];
                const int c = cb[rr*33 + j];
                if (v > best || (v == best && c < bc)) { best = v; bc = c; bj = j; }
            }
            es[rr*33 + bj] = -INFINITY;
            e[k] = errors[((size_t)(b*SS + bc))*4];   // errors[..., 0]
        }
        #pragma unroll 1
        for (int a = 1; a < 20; ++a) {     // insertion sort ascending
            const float v = e[a];
            int n = a;
            while (n > 0 && e[n-1] > v) { e[n] = e[n-1]; --n; }
            e[n] = v;
        }
        const float yp = y_pred[((size_t)(b*SS + sg))*4];
        const float yt = y[((size_t)(b*SS + sg))*4];
        float msum = 0.f;
        const size_t obase = ((size_t)(h*4 + b)*18)*2048 + sg;
        #pragma unroll 1
        for (int a = 0; a < 18; ++a) {
            const float alpha = c_alphas[a];
            const float beta  = 0.5f*alpha;
            const float pl = beta * 19.f;
            const int   il = (int)pl;
            const float fl = pl - (float)il;
            const float ql = e[il]*(1.f-fl) + e[il+1]*fl;
            const float qq = (1.f - alpha) + beta;
            const float ph = qq * 19.f;
            const int   ih = (int)ph;
            const float fh = ph - (float)ih;
            const float qh = e[ih]*(1.f-fh) + e[ih+1]*fh;
            msum += ql + qh;
            const size_t oidx = obase + (size_t)a*2048;
            out[OFF_YLOW  + oidx] = ql + yp;
            out[OFF_YHIGH + oidx] = qh + yp;
            out[OFF_QLOW  + oidx] = ql;
            out[OFF_QHIGH + oidx] = qh;
        }
        const float me = msum * (1.f/36.f);
        const float dd = yt - (me + yp);
        sq = dd*dd;
    }
    // wave-reduce sq (non-owners contribute 0), one atomic per wave
    #pragma unroll
    for (int o = 32; o > 0; o >>= 1) sq += __shfl_xor(sq, o);
    if (lane == 0) atomicAdd(&hacc[h], sq);
}

__global__ void k_init(float* __restrict__ hacc) {
    if (threadIdx.x < 4) hacc[threadIdx.x] = 0.f;
}

__global__ __launch_bounds__(256) void k_finalize(
    const float* __restrict__ y, const float* __restrict__ y_pred,
    const float* __restrict__ errors, const float* __restrict__ hacc,
    float* __restrict__ out)
{
    const int i = blockIdx.x*256 + threadIdx.x;
    if (i == 0)
        out[0] = (hacc[0]+hacc[1]+hacc[2]+hacc[3]) * (1.f/32768.f);
    if (i < 32768)      out[OFF_Y + i] = y[i];
    else if (i < 65536) out[OFF_YPRED + (i - 32768)] = y_pred[i - 32768];
    else if (i < 73728) { const int j = i - 65536; out[OFF_ERR + j] = errors[(size_t)j*4]; }
}

extern "C" void kernel_launch(void* const* d_in, const int* in_sizes, int n_in,
                              void* d_out, int out_size, void* d_ws, size_t ws_size,
                              hipStream_t stream)
{
    const float* Xt     = (const float*)d_in[0];
    const float* Xs     = (const float*)d_in[1];
    const float* errors = (const float*)d_in[2];
    const float* y      = (const float*)d_in[3];
    const float* y_pred = (const float*)d_in[4];
    const float* W1 = (const float*)d_in[5];   const float* b1 = (const float*)d_in[6];
    const float* W2 = (const float*)d_in[7];   const float* b2 = (const float*)d_in[8];
    const float* W3 = (const float*)d_in[9];   const float* b3 = (const float*)d_in[10];
    const float* W4 = (const float*)d_in[11];  const float* b4 = (const float*)d_in[12];
    const float* Wq = (const float*)d_in[13];  const float* bq = (const float*)d_in[14];
    const float* Wk = (const float*)d_in[15];  const float* bk = (const float*)d_in[16];
    const float* g_q    = (const float*)d_in[17];
    const float* beta_q = (const float*)d_in[18];
    const float* g_k    = (const float*)d_in[19];
    const float* beta_k = (const float*)d_in[20];

    float* out  = (float*)d_out;
    char*  base = (char*)d_ws;
    const size_t SLAB = (size_t)16*2048*128;               // 4,194,304 elements
    float* hacc = (float*)base;                            // 64B slot
    float* qf   = (float*)(base + 256);                    // 16MB
    float* kf   = qf + SLAB;                               // 16MB
    __hip_bfloat16* khi = (__hip_bfloat16*)(kf + SLAB);    // 8MB (swizzled)
    unsigned* wsk = (unsigned*)(khi + SLAB);               // 12.6MB

    k_init<<<1, 64, 0, stream>>>(hacc);
    k_mlp<<<2048, 64, 0, stream>>>(Xt, Xs, W1,b1,W2,b2,W3,b3,W4,b4,
                                   Wq,bq,Wk,bk,g_q,beta_q,g_k,beta_k,
                                   qf, kf, khi);
    k_scan<<<dim3(32,16,4), 256, 0, stream>>>(qf, khi, wsk);
    k_select<<<dim3(32,16), 256, 0, stream>>>(qf, kf, wsk, errors, y, y_pred, out, hacc);
    k_finalize<<<288, 256, 0, stream>>>(y, y_pred, errors, hacc, out);
}

// Round 11
// 695.206 us; speedup vs baseline: 1.1645x; 1.0273x over previous
//
#include <hip/hip_runtime.h>
#include <hip/hip_bf16.h>
#include <math.h>

// ConformHopfieldBatch: B=4 S=2048 IN=64 D=128 HID=400 H=4 K=20 NQ=18
// softmax monotone -> top_k(assoc) == top_k(raw scores). bf16-hi MFMA
// PREFILTER -> approx candidates; exact fp32 RESCORE -> true top-20 (R2).
// R10 postmortem: khi fragment-swizzle gained only ~40us; scan still ~280us
// vs ~40-90us issue models. Last untested model term: the depth-20 drop-min
// bubble = 46 ops/element in ONE serial dependency chain (worse if lowered
// as v_cmp+v_cndmask through vcc). R11: per lane TWO INDEPENDENT depth-12
// lists (reg-pairs {0,1}/{2,3}) -> ~30 ops/element, 2-way ILP.
// Safety (order stats): 64-col subset holding >=13 of needed top-21:
// P(Bin(21,1/32)>=13) ~1e-14; quad >=13 of 128 cols: ~4e-9 x 524k cells
// = 2e-3 expected misses -> inside 8x threshold slack. Owner: 8-way
// tournament merge (keys globally distinct: col bits) -> top-24 -> wsk.
// khi stays fragment-swizzled (R10: contiguous 1KB/wave scan loads).

#define SS 2048

typedef short short8v __attribute__((ext_vector_type(8)));
typedef float float4v __attribute__((ext_vector_type(4)));

__constant__ float c_alphas[18] = {0.05f,0.06f,0.08f,0.1f,0.12f,0.14f,0.15f,0.17f,
                                   0.19f,0.2f,0.21f,0.23f,0.25f,0.3f,0.35f,0.38f,0.4f,0.45f};

// output flat offsets (return-order concat)
#define OFF_Y      1
#define OFF_YPRED  32769
#define OFF_YLOW   65537ll
#define OFF_YHIGH  655361ll
#define OFF_ERR    1245185ll
#define OFF_QLOW   1253377ll
#define OFF_QHIGH  1843201ll

__device__ inline short f2bf_s(float f) {
    __hip_bfloat16 h = __float2bfloat16(f);
    return __builtin_bit_cast(short, h);
}
// monotone fp32 -> u32 map (order-preserving)
__device__ inline unsigned mono(float f) {
    unsigned u = __builtin_bit_cast(unsigned, f);
    return (u & 0x80000000u) ? ~u : (u | 0x80000000u);
}
// wave-uniform register broadcast (v_readlane_b32)
__device__ inline float rdlane(float v, int l) {
    return __builtin_bit_cast(float, __builtin_amdgcn_readlane(__builtin_bit_cast(int, v), l));
}
__device__ inline unsigned umin_(unsigned a, unsigned b) { return a < b ? a : b; }
__device__ inline unsigned umax_(unsigned a, unsigned b) { return a > b ? a : b; }

// ---------------------------------------------------------------------------
// Kernel A: fused MLP + LayerNorm + projection. 64 threads, 8 rows/block.
// Activations register-resident; readlane broadcast; no LDS.
// blocks 0..1023: true->q; 1024..2047: sim->k (fp32 + SWIZZLED bf16-hi).
// ---------------------------------------------------------------------------
__global__ __launch_bounds__(64, 1) void k_mlp(
    const float* __restrict__ Xt, const float* __restrict__ Xs,
    const float* __restrict__ W1, const float* __restrict__ b1,
    const float* __restrict__ W2, const float* __restrict__ b2,
    const float* __restrict__ W3, const float* __restrict__ b3,
    const float* __restrict__ W4, const float* __restrict__ b4,
    const float* __restrict__ Wq, const float* __restrict__ bq,
    const float* __restrict__ Wk, const float* __restrict__ bk,
    const float* __restrict__ g_q, const float* __restrict__ beta_q,
    const float* __restrict__ g_k, const float* __restrict__ beta_k,
    float* __restrict__ qf, float* __restrict__ kf,
    __hip_bfloat16* __restrict__ khi)
{
    const int t    = threadIdx.x;          // 0..63
    const int bi   = blockIdx.x;
    const int half = bi >> 10;             // 0:true/q 1:sim/k
    const int rbase = (bi & 1023) * 8;     // row group within half
    const float* X = half ? Xs : Xt;

    int jm[7];                             // clamped col ids for 400-wide layers
    #pragma unroll
    for (int cc = 0; cc < 7; ++cc) { int j = cc*64 + t; jm[cc] = (j < 400) ? j : 399; }

    // input rows into registers: lane t holds x[r][t]
    float xreg[8];
    #pragma unroll
    for (int r = 0; r < 8; ++r) xreg[r] = X[(size_t)(rbase + r)*64 + t];

    float A1[8][7], A2[8][7];

    // ---- layer 1: 64 -> 400 (relu), xreg -> A1 ----
    {
        #pragma unroll
        for (int r = 0; r < 8; ++r)
            #pragma unroll
            for (int cc = 0; cc < 7; ++cc) A1[r][cc] = 0.f;
        #pragma unroll 4
        for (int il = 0; il < 64; ++il) {
            float wv[7];
            #pragma unroll
            for (int cc = 0; cc < 7; ++cc) wv[cc] = W1[il*400 + jm[cc]];
            #pragma unroll
            for (int r = 0; r < 8; ++r) {
                const float x = rdlane(xreg[r], il);
                #pragma unroll
                for (int cc = 0; cc < 7; ++cc) A1[r][cc] = fmaf(x, wv[cc], A1[r][cc]);
            }
        }
        #pragma unroll
        for (int cc = 0; cc < 7; ++cc) {
            const float bb = b1[jm[cc]];
            #pragma unroll
            for (int r = 0; r < 8; ++r) A1[r][cc] = fmaxf(A1[r][cc] + bb, 0.f);
        }
    }

    // ---- layer 2: 400 -> 400 (relu), A1 -> A2 ----
    {
        #pragma unroll
        for (int r = 0; r < 8; ++r)
            #pragma unroll
            for (int cc = 0; cc < 7; ++cc) A2[r][cc] = 0.f;
        #pragma unroll
        for (int cs = 0; cs < 7; ++cs) {
            const int ilim = (cs == 6) ? 16 : 64;
            #pragma unroll 4
            for (int il = 0; il < ilim; ++il) {
                const int i = cs*64 + il;
                float wv[7];
                #pragma unroll
                for (int cc = 0; cc < 7; ++cc) wv[cc] = W2[i*400 + jm[cc]];
                #pragma unroll
                for (int r = 0; r < 8; ++r) {
                    const float x = rdlane(A1[r][cs], il);
                    #pragma unroll
                    for (int cc = 0; cc < 7; ++cc) A2[r][cc] = fmaf(x, wv[cc], A2[r][cc]);
                }
            }
        }
        #pragma unroll
        for (int cc = 0; cc < 7; ++cc) {
            const float bb = b2[jm[cc]];
            #pragma unroll
            for (int r = 0; r < 8; ++r) A2[r][cc] = fmaxf(A2[r][cc] + bb, 0.f);
        }
    }

    // ---- layer 3: 400 -> 400 (relu), A2 -> A1 ----
    {
        #pragma unroll
        for (int r = 0; r < 8; ++r)
            #pragma unroll
            for (int cc = 0; cc < 7; ++cc) A1[r][cc] = 0.f;
        #pragma unroll
        for (int cs = 0; cs < 7; ++cs) {
            const int ilim = (cs == 6) ? 16 : 64;
            #pragma unroll 4
            for (int il = 0; il < ilim; ++il) {
                const int i = cs*64 + il;
                float wv[7];
                #pragma unroll
                for (int cc = 0; cc < 7; ++cc) wv[cc] = W3[i*400 + jm[cc]];
                #pragma unroll
                for (int r = 0; r < 8; ++r) {
                    const float x = rdlane(A2[r][cs], il);
                    #pragma unroll
                    for (int cc = 0; cc < 7; ++cc) A1[r][cc] = fmaf(x, wv[cc], A1[r][cc]);
                }
            }
        }
        #pragma unroll
        for (int cc = 0; cc < 7; ++cc) {
            const float bb = b3[jm[cc]];
            #pragma unroll
            for (int r = 0; r < 8; ++r) A1[r][cc] = fmaxf(A1[r][cc] + bb, 0.f);
        }
    }

    // ---- layer 4: 400 -> 128 (no relu), A1 -> acc4 (lane t: cols t, 64+t) ----
    float acc4[8][2];
    {
        #pragma unroll
        for (int r = 0; r < 8; ++r) { acc4[r][0] = 0.f; acc4[r][1] = 0.f; }
        #pragma unroll
        for (int cs = 0; cs < 7; ++cs) {
            const int ilim = (cs == 6) ? 16 : 64;
            #pragma unroll 4
            for (int il = 0; il < ilim; ++il) {
                const int i = cs*64 + il;
                const float w0 = W4[i*128 + t];
                const float w1 = W4[i*128 + 64 + t];
                #pragma unroll
                for (int r = 0; r < 8; ++r) {
                    const float x = rdlane(A1[r][cs], il);
                    acc4[r][0] = fmaf(x, w0, acc4[r][0]);
                    acc4[r][1] = fmaf(x, w1, acc4[r][1]);
                }
            }
        }
        const float bb0 = b4[t], bb1 = b4[64 + t];
        #pragma unroll
        for (int r = 0; r < 8; ++r) { acc4[r][0] += bb0; acc4[r][1] += bb1; }
    }

    // ---- LayerNorm over 128 (values spread: 2/lane x 64 lanes) ----
    float lnv[8][2];
    {
        const float* g  = half ? g_k : g_q;
        const float* be = half ? beta_k : beta_q;
        const float gl0 = g[t],  gl1 = g[64 + t];
        const float bl0 = be[t], bl1 = be[64 + t];
        #pragma unroll
        for (int r = 0; r < 8; ++r) {
            float s = acc4[r][0] + acc4[r][1];
            #pragma unroll
            for (int o = 32; o > 0; o >>= 1) s += __shfl_xor(s, o);
            const float mu = s * (1.f/128.f);
            const float d0 = acc4[r][0] - mu, d1 = acc4[r][1] - mu;
            float vs = d0*d0 + d1*d1;
            #pragma unroll
            for (int o = 32; o > 0; o >>= 1) vs += __shfl_xor(vs, o);
            const float rstd = rsqrtf(vs * (1.f/128.f) + 1e-5f);
            lnv[r][0] = d0*rstd*gl0 + bl0;
            lnv[r][1] = d1*rstd*gl1 + bl1;
        }
    }

    // ---- projection 128 -> 512 (8 cols/lane), write fp32 (+swizzled bf16) ----
    {
        const float* Wp = half ? Wk : Wq;
        const float* bp = half ? bk : bq;
        float* of = half ? kf : qf;
        float accp[8][8];
        #pragma unroll
        for (int r = 0; r < 8; ++r)
            #pragma unroll
            for (int cc = 0; cc < 8; ++cc) accp[r][cc] = 0.f;
        #pragma unroll
        for (int cs = 0; cs < 2; ++cs) {
            #pragma unroll 4
            for (int il = 0; il < 64; ++il) {
                const int i = cs*64 + il;
                float wv[8];
                #pragma unroll
                for (int cc = 0; cc < 8; ++cc) wv[cc] = Wp[i*512 + cc*64 + t];
                #pragma unroll
                for (int r = 0; r < 8; ++r) {
                    const float x = rdlane(lnv[r][cs], il);
                    #pragma unroll
                    for (int cc = 0; cc < 8; ++cc) accp[r][cc] = fmaf(x, wv[cc], accp[r][cc]);
                }
            }
        }
        float bpv[8];
        #pragma unroll
        for (int cc = 0; cc < 8; ++cc) bpv[cc] = bp[cc*64 + t];
        #pragma unroll
        for (int r = 0; r < 8; ++r) {
            const int gidx = rbase + r;
            const int bb = gidx >> 11, s = gidx & 2047;
            const int T = s >> 4, m16s = s & 15;
            #pragma unroll
            for (int cc = 0; cc < 8; ++cc) {
                const int j  = cc*64 + t;
                const int hh = j >> 7, d = j & 127;
                const float v = accp[r][cc] + bpv[cc];
                const size_t dst = ((size_t)(bb*4 + hh)*2048 + s)*128 + d;
                of[dst] = v;
                if (half) {
                    const int ks = d >> 5, qd = (d & 31) >> 3, jj = d & 7;
                    const size_t so = (size_t)(bb*4 + hh)*262144
                                    + (size_t)T*2048 + ks*512 + qd*128 + m16s*8 + jj;
                    khi[so] = __float2bfloat16(v);
                }
            }
        }
    }
}

// ---------------------------------------------------------------------------
// Kernel B: MFMA scan over an m-quarter (512 cols). Per lane: TWO independent
// sorted depth-12 key lists (reg-pair {0,1} -> KA, {2,3} -> KB; 2-way ILP,
// 11-swap bubbles). Dump 2x12 desc per (row,quad); owner (quad0) 8-way
// tournament-merges the row's 8 lists -> top-24 -> wsk.
// khi fragment-swizzled: per cti the 4 ks-loads are contiguous 1KB/wave.
// ---------------------------------------------------------------------------
__global__ __launch_bounds__(256, 4) void k_scan(
    const float* __restrict__ qf, const __hip_bfloat16* __restrict__ khi,
    unsigned* __restrict__ wsk)
{
    __shared__ unsigned kd[64*97];     // 24.8KB; row stride 97 (odd) bank-safe

    const int tid   = threadIdx.x;
    const int stile = blockIdx.x;      // 0..31
    const int hb    = blockIdx.y;      // 0..15
    const int mq    = blockIdx.z;      // 0..3

    const int lane = tid & 63;
    const int w    = tid >> 6;
    const int m16  = lane & 15;
    const int quad = lane >> 4;

    const size_t slab = (size_t)hb * 2048;
    const __hip_bfloat16* slabp = khi + (size_t)hb * 262144;   // swizzled slab

    const int sg_my = stile*64 + w*16 + m16;

    // Q fragment (B operand): B[n=m16][k=quad*8+j+ks*32] = q[w*16+n][k]
    short8v bq_[4];
    {
        const float* qp = qf + (slab + sg_my)*128 + quad*8;
        #pragma unroll
        for (int ks = 0; ks < 4; ++ks) {
            const float4 x0 = *(const float4*)(qp + ks*32);
            const float4 x1 = *(const float4*)(qp + ks*32 + 4);
            short8v tt;
            tt[0]=f2bf_s(x0.x); tt[1]=f2bf_s(x0.y); tt[2]=f2bf_s(x0.z); tt[3]=f2bf_s(x0.w);
            tt[4]=f2bf_s(x1.x); tt[5]=f2bf_s(x1.y); tt[6]=f2bf_s(x1.z); tt[7]=f2bf_s(x1.w);
            bq_[ks] = tt;
        }
    }

    unsigned KA[12], KB[12];           // ascending; [0] = min
    #pragma unroll
    for (int n = 0; n < 12; ++n) { KA[n] = 0u; KB[n] = 0u; }

    #pragma unroll 1
    for (int cti = 0; cti < 32; ++cti) {
        const int T = mq*32 + cti;     // global 16-col tile id
        const __hip_bfloat16* kp = slabp + (size_t)T*2048 + lane*8;
        float4v acc = (float4v){0.f,0.f,0.f,0.f};
        #pragma unroll
        for (int ks = 0; ks < 4; ++ks) {
            const short8v ka = *(const short8v*)(kp + ks*512);
            acc = __builtin_amdgcn_mfma_f32_16x16x32_bf16(ka, bq_[ks], acc, 0, 0, 0);
        }
        const int cb = T*16 + quad*4;
        // two interleaved independent inserts: (reg0->KA | reg2->KB),
        // then (reg1->KA | reg3->KB)  -- 2-way ILP on the swap chains
        #pragma unroll
        for (int ph = 0; ph < 2; ++ph) {
            {   // KA insert: reg = ph
                const int m = cb + ph;
                unsigned key = (mono(acc[ph]) & 0xFFFFF800u) | (unsigned)m;
                key = (m == sg_my) ? 0u : key;
                KA[0] = umax_(KA[0], key);
                #pragma unroll
                for (int i = 0; i < 11; ++i) {
                    const unsigned a = KA[i], c = KA[i+1];
                    KA[i]   = umin_(a, c);
                    KA[i+1] = umax_(a, c);
                }
            }
            {   // KB insert: reg = 2+ph
                const int m = cb + 2 + ph;
                unsigned key = (mono(acc[2+ph]) & 0xFFFFF800u) | (unsigned)m;
                key = (m == sg_my) ? 0u : key;
                KB[0] = umax_(KB[0], key);
                #pragma unroll
                for (int i = 0; i < 11; ++i) {
                    const unsigned a = KB[i], c = KB[i+1];
                    KB[i]   = umin_(a, c);
                    KB[i+1] = umax_(a, c);
                }
            }
        }
    }

    // dump: per (row, quad) two desc 12-lists at kd[rr*97 + (quad*2+l)*12 + n]
    const int rr = w*16 + m16;
    #pragma unroll
    for (int n = 0; n < 12; ++n) {
        kd[rr*97 + (quad*2 + 0)*12 + n] = KA[11 - n];
        kd[rr*97 + (quad*2 + 1)*12 + n] = KB[11 - n];
    }
    __syncthreads();

    // owner (quad 0): 8-way tournament merge -> top-24 -> ws (desc).
    // Keys are globally distinct (low 11 bits = col) -> '>' is a total order.
    if (quad == 0) {
        const unsigned* R = &kd[rr*97];
        int q0=0,q1=0,q2=0,q3=0,q4=0,q5=0,q6=0,q7=0;
        const size_t base = (size_t)hb*2048 + stile*64 + rr;
        #pragma unroll 1
        for (int n = 0; n < 24; ++n) {
            const unsigned h0 = (q0<12)?R[  0+q0]:0u;
            const unsigned h1 = (q1<12)?R[ 12+q1]:0u;
            const unsigned h2 = (q2<12)?R[ 24+q2]:0u;
            const unsigned h3 = (q3<12)?R[ 36+q3]:0u;
            const unsigned h4 = (q4<12)?R[ 48+q4]:0u;
            const unsigned h5 = (q5<12)?R[ 60+q5]:0u;
            const unsigned h6 = (q6<12)?R[ 72+q6]:0u;
            const unsigned h7 = (q7<12)?R[ 84+q7]:0u;
            unsigned bv = h0; int bs = 0;
            if (h1 > bv) { bv = h1; bs = 1; }
            if (h2 > bv) { bv = h2; bs = 2; }
            if (h3 > bv) { bv = h3; bs = 3; }
            if (h4 > bv) { bv = h4; bs = 4; }
            if (h5 > bv) { bv = h5; bs = 5; }
            if (h6 > bv) { bv = h6; bs = 6; }
            if (h7 > bv) { bv = h7; bs = 7; }
            q0 += (bs==0); q1 += (bs==1); q2 += (bs==2); q3 += (bs==3);
            q4 += (bs==4); q5 += (bs==5); q6 += (bs==6); q7 += (bs==7);
            wsk[(size_t)(mq*24 + n)*32768 + base] = bv;
        }
    }
}

// ---------------------------------------------------------------------------
// Kernel C: per row merge 4x24 approx keys -> top-32 -> cooperative exact
// fp32 rescore -> exact top-20 -> quantiles + outputs + score accumulation.
// ---------------------------------------------------------------------------
__global__ __launch_bounds__(256, 4) void k_select(
    const float* __restrict__ qf, const float* __restrict__ kf,
    const unsigned* __restrict__ wsk,
    const float* __restrict__ errors, const float* __restrict__ y,
    const float* __restrict__ y_pred,
    float* __restrict__ out, float* __restrict__ hacc)
{
    __shared__ unsigned kd[64*4*25];       // 25.6KB (pad 25)
    __shared__ unsigned short cb[64*33];   // 4.2KB candidate cols
    __shared__ float es[64*33];            // 8.4KB exact scores
    __shared__ float ebuf[64*21];          // 5.4KB sort buffer

    const int tid   = threadIdx.x;
    const int stile = blockIdx.x;          // 0..31
    const int hb    = blockIdx.y;          // 0..15
    const int b     = hb >> 2;
    const int h     = hb & 3;

    const int lane = tid & 63;
    const int w    = tid >> 6;
    const int m16  = lane & 15;
    const int quad = lane >> 4;
    const int rr   = w*16 + m16;
    const int sg   = stile*64 + rr;

    const size_t base = (size_t)hb*2048 + sg;
    // lane loads mq=quad's 24 keys (coalesced across rows)
    #pragma unroll 1
    for (int n = 0; n < 24; ++n)
        kd[(rr*4 + quad)*25 + n] = wsk[(size_t)(quad*24 + n)*32768 + base];
    __syncthreads();

    // owner: merge 4 sorted-desc 24-lists -> approx-top-32 cols
    if (quad == 0) {
        const unsigned* L0 = &kd[(rr*4 + 0)*25];
        const unsigned* L1 = &kd[(rr*4 + 1)*25];
        const unsigned* L2 = &kd[(rr*4 + 2)*25];
        const unsigned* L3 = &kd[(rr*4 + 3)*25];
        int p0 = 0, p1 = 0, p2 = 0, p3 = 0;
        #pragma unroll 1
        for (int n = 0; n < 32; ++n) {
            const unsigned h0 = (p0 < 24) ? L0[p0] : 0u;
            const unsigned h1 = (p1 < 24) ? L1[p1] : 0u;
            const unsigned h2 = (p2 < 24) ? L2[p2] : 0u;
            const unsigned h3 = (p3 < 24) ? L3[p3] : 0u;
            unsigned bv = h0; int bs = 0;
            if (h1 > bv) { bv = h1; bs = 1; }
            if (h2 > bv) { bv = h2; bs = 2; }
            if (h3 > bv) { bv = h3; bs = 3; }
            if (bs == 0) ++p0; else if (bs == 1) ++p1; else if (bs == 2) ++p2; else ++p3;
            cb[rr*33 + n] = (unsigned short)(bv & 0x7FFu);
        }
    }
    __syncthreads();

    // cooperative exact rescore of the 32 candidates
    const size_t slab = (size_t)hb * 2048;
    const float* qrow_p = qf + (slab + sg)*128;
    float4 qseg[8];
    #pragma unroll
    for (int u = 0; u < 8; ++u)
        qseg[u] = *(const float4*)(qrow_p + quad*4 + u*16);
    const float* kslab = kf + slab*128;
    #pragma unroll 1
    for (int n = 0; n < 32; ++n) {
        const int col = cb[rr*33 + n];
        const float* kc = kslab + (size_t)col*128 + quad*4;
        float4v s = (float4v){0.f,0.f,0.f,0.f};
        #pragma unroll
        for (int u = 0; u < 8; ++u) {
            const float4 kv = *(const float4*)(kc + u*16);
            s[0] = fmaf(qseg[u].x, kv.x, s[0]);
            s[1] = fmaf(qseg[u].y, kv.y, s[1]);
            s[2] = fmaf(qseg[u].z, kv.z, s[2]);
            s[3] = fmaf(qseg[u].w, kv.w, s[3]);
        }
        float v = (s[0] + s[1]) + (s[2] + s[3]);
        v += __shfl_xor(v, 16);
        v += __shfl_xor(v, 32);
        if (quad == 0) es[rr*33 + n] = v;
    }

    // owner: exact top-20 selection (desc, col asc ties) + quantiles
    float sq = 0.f;
    if (quad == 0) {
        float* e = &ebuf[rr*21];
        #pragma unroll 1
        for (int k = 0; k < 20; ++k) {
            float best = -INFINITY; int bc = 4096, bj = 0;
            #pragma unroll 1
            for (int j = 0; j < 32; ++j) {
                const float v = es[rr*33 + j];
                const int c = cb[rr*33 + j];
                if (v > best || (v == best && c < bc)) { best = v; bc = c; bj = j; }
            }
            es[rr*33 + bj] = -INFINITY;
            e[k] = errors[((size_t)(b*SS + bc))*4];   // errors[..., 0]
        }
        #pragma unroll 1
        for (int a = 1; a < 20; ++a) {     // insertion sort ascending
            const float v = e[a];
            int n = a;
            while (n > 0 && e[n-1] > v) { e[n] = e[n-1]; --n; }
            e[n] = v;
        }
        const float yp = y_pred[((size_t)(b*SS + sg))*4];
        const float yt = y[((size_t)(b*SS + sg))*4];
        float msum = 0.f;
        const size_t obase = ((size_t)(h*4 + b)*18)*2048 + sg;
        #pragma unroll 1
        for (int a = 0; a < 18; ++a) {
            const float alpha = c_alphas[a];
            const float beta  = 0.5f*alpha;
            const float pl = beta * 19.f;
            const int   il = (int)pl;
            const float fl = pl - (float)il;
            const float ql = e[il]*(1.f-fl) + e[il+1]*fl;
            const float qq = (1.f - alpha) + beta;
            const float ph = qq * 19.f;
            const int   ih = (int)ph;
            const float fh = ph - (float)ih;
            const float qh = e[ih]*(1.f-fh) + e[ih+1]*fh;
            msum += ql + qh;
            const size_t oidx = obase + (size_t)a*2048;
            out[OFF_YLOW  + oidx] = ql + yp;
            out[OFF_YHIGH + oidx] = qh + yp;
            out[OFF_QLOW  + oidx] = ql;
            out[OFF_QHIGH + oidx] = qh;
        }
        const float me = msum * (1.f/36.f);
        const float dd = yt - (me + yp);
        sq = dd*dd;
    }
    // wave-reduce sq (non-owners contribute 0), one atomic per wave
    #pragma unroll
    for (int o = 32; o > 0; o >>= 1) sq += __shfl_xor(sq, o);
    if (lane == 0) atomicAdd(&hacc[h], sq);
}

__global__ void k_init(float* __restrict__ hacc) {
    if (threadIdx.x < 4) hacc[threadIdx.x] = 0.f;
}

__global__ __launch_bounds__(256) void k_finalize(
    const float* __restrict__ y, const float* __restrict__ y_pred,
    const float* __restrict__ errors, const float* __restrict__ hacc,
    float* __restrict__ out)
{
    const int i = blockIdx.x*256 + threadIdx.x;
    if (i == 0)
        out[0] = (hacc[0]+hacc[1]+hacc[2]+hacc[3]) * (1.f/32768.f);
    if (i < 32768)      out[OFF_Y + i] = y[i];
    else if (i < 65536) out[OFF_YPRED + (i - 32768)] = y_pred[i - 32768];
    else if (i < 73728) { const int j = i - 65536; out[OFF_ERR + j] = errors[(size_t)j*4]; }
}

extern "C" void kernel_launch(void* const* d_in, const int* in_sizes, int n_in,
                              void* d_out, int out_size, void* d_ws, size_t ws_size,
                              hipStream_t stream)
{
    const float* Xt     = (const float*)d_in[0];
    const float* Xs     = (const float*)d_in[1];
    const float* errors = (const float*)d_in[2];
    const float* y      = (const float*)d_in[3];
    const float* y_pred = (const float*)d_in[4];
    const float* W1 = (const float*)d_in[5];   const float* b1 = (const float*)d_in[6];
    const float* W2 = (const float*)d_in[7];   const float* b2 = (const float*)d_in[8];
    const float* W3 = (const float*)d_in[9];   const float* b3 = (const float*)d_in[10];
    const float* W4 = (const float*)d_in[11];  const float* b4 = (const float*)d_in[12];
    const float* Wq = (const float*)d_in[13];  const float* bq = (const float*)d_in[14];
    const float* Wk = (const float*)d_in[15];  const float* bk = (const float*)d_in[16];
    const float* g_q    = (const float*)d_in[17];
    const float* beta_q = (const float*)d_in[18];
    const float* g_k    = (const float*)d_in[19];
    const float* beta_k = (const float*)d_in[20];

    float* out  = (float*)d_out;
    char*  base = (char*)d_ws;
    const size_t SLAB = (size_t)16*2048*128;               // 4,194,304 elements
    float* hacc = (float*)base;                            // 64B slot
    float* qf   = (float*)(base + 256);                    // 16MB
    float* kf   = qf + SLAB;                               // 16MB
    __hip_bfloat16* khi = (__hip_bfloat16*)(kf + SLAB);    // 8MB (swizzled)
    unsigned* wsk = (unsigned*)(khi + SLAB);               // 12.6MB

    k_init<<<1, 64, 0, stream>>>(hacc);
    k_mlp<<<2048, 64, 0, stream>>>(Xt, Xs, W1,b1,W2,b2,W3,b3,W4,b4,
                                   Wq,bq,Wk,bk,g_q,beta_q,g_k,beta_k,
                                   qf, kf, khi);
    k_scan<<<dim3(32,16,4), 256, 0, stream>>>(qf, khi, wsk);
    k_select<<<dim3(32,16), 256, 0, stream>>>(qf, kf, wsk, errors, y, y_pred, out, hacc);
    k_finalize<<<288, 256, 0, stream>>>(y, y_pred, errors, hacc, out);
}

// Round 12
// 693.217 us; speedup vs baseline: 1.1678x; 1.0029x over previous
//
#include <hip/hip_runtime.h>
#include <hip/hip_bf16.h>
#include <math.h>

// ConformHopfieldBatch: B=4 S=2048 IN=64 D=128 HID=400 H=4 K=20 NQ=18
// softmax monotone -> top_k(assoc) == top_k(raw scores). bf16-hi MFMA
// PREFILTER -> approx candidates; exact fp32 RESCORE -> true top-20 (R2).
// R11 postmortem: insert-depth/ILP change bought only 19us -> insert chain
// exonerated (along with divergence/I$/spill/scatter across R6-R11).
// k_mlp is 54% of wall (374us, VALUBusy 70%, issue-bound at 2 waves/SIMD).
// R12: PACKED FP32 (v_pk_fma_f32, gfx90a+) -- accumulators as float2
// ext-vectors packed across OUTPUT COLUMNS; per-column i-order unchanged ->
// bit-identical outputs. 7 scalar FMA -> 4 pk-FMA per (row,il) step.
// Same packing in k_select rescore partials. Scan unchanged from R11.

#define SS 2048

typedef short short8v __attribute__((ext_vector_type(8)));
typedef float float4v __attribute__((ext_vector_type(4)));
typedef float float2v __attribute__((ext_vector_type(2)));

__constant__ float c_alphas[18] = {0.05f,0.06f,0.08f,0.1f,0.12f,0.14f,0.15f,0.17f,
                                   0.19f,0.2f,0.21f,0.23f,0.25f,0.3f,0.35f,0.38f,0.4f,0.45f};

// output flat offsets (return-order concat)
#define OFF_Y      1
#define OFF_YPRED  32769
#define OFF_YLOW   65537ll
#define OFF_YHIGH  655361ll
#define OFF_ERR    1245185ll
#define OFF_QLOW   1253377ll
#define OFF_QHIGH  1843201ll

__device__ inline short f2bf_s(float f) {
    __hip_bfloat16 h = __float2bfloat16(f);
    return __builtin_bit_cast(short, h);
}
// monotone fp32 -> u32 map (order-preserving)
__device__ inline unsigned mono(float f) {
    unsigned u = __builtin_bit_cast(unsigned, f);
    return (u & 0x80000000u) ? ~u : (u | 0x80000000u);
}
// wave-uniform register broadcast (v_readlane_b32)
__device__ inline float rdlane(float v, int l) {
    return __builtin_bit_cast(float, __builtin_amdgcn_readlane(__builtin_bit_cast(int, v), l));
}
__device__ inline unsigned umin_(unsigned a, unsigned b) { return a < b ? a : b; }
__device__ inline unsigned umax_(unsigned a, unsigned b) { return a > b ? a : b; }
__device__ inline float2v pkfma(float x, float2v w, float2v a) {
    return __builtin_elementwise_fma((float2v){x, x}, w, a);
}

// ---------------------------------------------------------------------------
// Kernel A: fused MLP + LayerNorm + projection. 64 threads, 8 rows/block.
// Activations register-resident as float2 packed col-pairs (v_pk_fma_f32);
// readlane broadcast; no LDS. Lane t owns virtual cols {cc*64+t, cc=0..7}
// (col clamped to 399 for cc=7 in 400-wide layers; dummy discarded).
// Per-column FMA i-order identical to scalar version -> bit-identical.
// ---------------------------------------------------------------------------
__global__ __launch_bounds__(64, 1) void k_mlp(
    const float* __restrict__ Xt, const float* __restrict__ Xs,
    const float* __restrict__ W1, const float* __restrict__ b1,
    const float* __restrict__ W2, const float* __restrict__ b2,
    const float* __restrict__ W3, const float* __restrict__ b3,
    const float* __restrict__ W4, const float* __restrict__ b4,
    const float* __restrict__ Wq, const float* __restrict__ bq,
    const float* __restrict__ Wk, const float* __restrict__ bk,
    const float* __restrict__ g_q, const float* __restrict__ beta_q,
    const float* __restrict__ g_k, const float* __restrict__ beta_k,
    float* __restrict__ qf, float* __restrict__ kf,
    __hip_bfloat16* __restrict__ khi)
{
    const int t    = threadIdx.x;          // 0..63
    const int bi   = blockIdx.x;
    const int half = bi >> 10;             // 0:true/q 1:sim/k
    const int rbase = (bi & 1023) * 8;     // row group within half
    const float* X = half ? Xs : Xt;

    int jm[8];                             // clamped col ids (400-wide layers)
    #pragma unroll
    for (int cc = 0; cc < 8; ++cc) { int j = cc*64 + t; jm[cc] = (j < 400) ? j : 399; }

    // input rows into registers: lane t holds x[r][t]
    float xreg[8];
    #pragma unroll
    for (int r = 0; r < 8; ++r) xreg[r] = X[(size_t)(rbase + r)*64 + t];

    float2v A1[8][4], A2[8][4];            // packed col-pairs (2p, 2p+1)

    // ---- layer 1: 64 -> 400 (relu), xreg -> A1 ----
    {
        #pragma unroll
        for (int r = 0; r < 8; ++r)
            #pragma unroll
            for (int p = 0; p < 4; ++p) A1[r][p] = (float2v){0.f, 0.f};
        #pragma unroll 4
        for (int il = 0; il < 64; ++il) {
            float2v wv[4];
            #pragma unroll
            for (int p = 0; p < 4; ++p)
                wv[p] = (float2v){W1[il*400 + jm[2*p]], W1[il*400 + jm[2*p+1]]};
            #pragma unroll
            for (int r = 0; r < 8; ++r) {
                const float x = rdlane(xreg[r], il);
                #pragma unroll
                for (int p = 0; p < 4; ++p) A1[r][p] = pkfma(x, wv[p], A1[r][p]);
            }
        }
        #pragma unroll
        for (int p = 0; p < 4; ++p) {
            const float2v bb = (float2v){b1[jm[2*p]], b1[jm[2*p+1]]};
            #pragma unroll
            for (int r = 0; r < 8; ++r)
                A1[r][p] = __builtin_elementwise_max(A1[r][p] + bb, (float2v){0.f, 0.f});
        }
    }

    // ---- layer 2: 400 -> 400 (relu), A1 -> A2 ----
    {
        #pragma unroll
        for (int r = 0; r < 8; ++r)
            #pragma unroll
            for (int p = 0; p < 4; ++p) A2[r][p] = (float2v){0.f, 0.f};
        #pragma unroll
        for (int cs = 0; cs < 7; ++cs) {
            const int ilim = (cs == 6) ? 16 : 64;
            #pragma unroll 4
            for (int il = 0; il < ilim; ++il) {
                const int i = cs*64 + il;
                float2v wv[4];
                #pragma unroll
                for (int p = 0; p < 4; ++p)
                    wv[p] = (float2v){W2[i*400 + jm[2*p]], W2[i*400 + jm[2*p+1]]};
                #pragma unroll
                for (int r = 0; r < 8; ++r) {
                    const float x = rdlane(A1[r][cs >> 1][cs & 1], il);
                    #pragma unroll
                    for (int p = 0; p < 4; ++p) A2[r][p] = pkfma(x, wv[p], A2[r][p]);
                }
            }
        }
        #pragma unroll
        for (int p = 0; p < 4; ++p) {
            const float2v bb = (float2v){b2[jm[2*p]], b2[jm[2*p+1]]};
            #pragma unroll
            for (int r = 0; r < 8; ++r)
                A2[r][p] = __builtin_elementwise_max(A2[r][p] + bb, (float2v){0.f, 0.f});
        }
    }

    // ---- layer 3: 400 -> 400 (relu), A2 -> A1 ----
    {
        #pragma unroll
        for (int r = 0; r < 8; ++r)
            #pragma unroll
            for (int p = 0; p < 4; ++p) A1[r][p] = (float2v){0.f, 0.f};
        #pragma unroll
        for (int cs = 0; cs < 7; ++cs) {
            const int ilim = (cs == 6) ? 16 : 64;
            #pragma unroll 4
            for (int il = 0; il < ilim; ++il) {
                const int i = cs*64 + il;
                float2v wv[4];
                #pragma unroll
                for (int p = 0; p < 4; ++p)
                    wv[p] = (float2v){W3[i*400 + jm[2*p]], W3[i*400 + jm[2*p+1]]};
                #pragma unroll
                for (int r = 0; r < 8; ++r) {
                    const float x = rdlane(A2[r][cs >> 1][cs & 1], il);
                    #pragma unroll
                    for (int p = 0; p < 4; ++p) A1[r][p] = pkfma(x, wv[p], A1[r][p]);
                }
            }
        }
        #pragma unroll
        for (int p = 0; p < 4; ++p) {
            const float2v bb = (float2v){b3[jm[2*p]], b3[jm[2*p+1]]};
            #pragma unroll
            for (int r = 0; r < 8; ++r)
                A1[r][p] = __builtin_elementwise_max(A1[r][p] + bb, (float2v){0.f, 0.f});
        }
    }

    // ---- layer 4: 400 -> 128 (no relu): lane t owns col pair (t, 64+t) ----
    float2v acc4[8];
    {
        #pragma unroll
        for (int r = 0; r < 8; ++r) acc4[r] = (float2v){0.f, 0.f};
        #pragma unroll
        for (int cs = 0; cs < 7; ++cs) {
            const int ilim = (cs == 6) ? 16 : 64;
            #pragma unroll 4
            for (int il = 0; il < ilim; ++il) {
                const int i = cs*64 + il;
                const float2v wv = (float2v){W4[i*128 + t], W4[i*128 + 64 + t]};
                #pragma unroll
                for (int r = 0; r < 8; ++r) {
                    const float x = rdlane(A1[r][cs >> 1][cs & 1], il);
                    acc4[r] = pkfma(x, wv, acc4[r]);
                }
            }
        }
        const float2v bb = (float2v){b4[t], b4[64 + t]};
        #pragma unroll
        for (int r = 0; r < 8; ++r) acc4[r] = acc4[r] + bb;
    }

    // ---- LayerNorm over 128 (2 values/lane x 64 lanes) ----
    float2v lnv[8];
    {
        const float* g  = half ? g_k : g_q;
        const float* be = half ? beta_k : beta_q;
        const float gl0 = g[t],  gl1 = g[64 + t];
        const float bl0 = be[t], bl1 = be[64 + t];
        #pragma unroll
        for (int r = 0; r < 8; ++r) {
            float s = acc4[r][0] + acc4[r][1];
            #pragma unroll
            for (int o = 32; o > 0; o >>= 1) s += __shfl_xor(s, o);
            const float mu = s * (1.f/128.f);
            const float d0 = acc4[r][0] - mu, d1 = acc4[r][1] - mu;
            float vs = d0*d0 + d1*d1;
            #pragma unroll
            for (int o = 32; o > 0; o >>= 1) vs += __shfl_xor(vs, o);
            const float rstd = rsqrtf(vs * (1.f/128.f) + 1e-5f);
            lnv[r][0] = d0*rstd*gl0 + bl0;
            lnv[r][1] = d1*rstd*gl1 + bl1;
        }
    }

    // ---- projection 128 -> 512 (8 cols = 4 pairs/lane) ----
    {
        const float* Wp = half ? Wk : Wq;
        const float* bp = half ? bk : bq;
        float* of = half ? kf : qf;
        float2v accp[8][4];
        #pragma unroll
        for (int r = 0; r < 8; ++r)
            #pragma unroll
            for (int p = 0; p < 4; ++p) accp[r][p] = (float2v){0.f, 0.f};
        #pragma unroll
        for (int cs = 0; cs < 2; ++cs) {
            #pragma unroll 4
            for (int il = 0; il < 64; ++il) {
                const int i = cs*64 + il;
                float2v wv[4];
                #pragma unroll
                for (int p = 0; p < 4; ++p)
                    wv[p] = (float2v){Wp[i*512 + (2*p)*64 + t], Wp[i*512 + (2*p+1)*64 + t]};
                #pragma unroll
                for (int r = 0; r < 8; ++r) {
                    const float x = rdlane(lnv[r][cs], il);
                    #pragma unroll
                    for (int p = 0; p < 4; ++p) accp[r][p] = pkfma(x, wv[p], accp[r][p]);
                }
            }
        }
        float bpv[8];
        #pragma unroll
        for (int cc = 0; cc < 8; ++cc) bpv[cc] = bp[cc*64 + t];
        #pragma unroll
        for (int r = 0; r < 8; ++r) {
            const int gidx = rbase + r;
            const int bb = gidx >> 11, s = gidx & 2047;
            const int T = s >> 4, m16s = s & 15;
            #pragma unroll
            for (int cc = 0; cc < 8; ++cc) {
                const int j  = cc*64 + t;
                const int hh = j >> 7, d = j & 127;
                const float v = accp[r][cc >> 1][cc & 1] + bpv[cc];
                const size_t dst = ((size_t)(bb*4 + hh)*2048 + s)*128 + d;
                of[dst] = v;
                if (half) {
                    const int ks = d >> 5, qd = (d & 31) >> 3, jj = d & 7;
                    const size_t so = (size_t)(bb*4 + hh)*262144
                                    + (size_t)T*2048 + ks*512 + qd*128 + m16s*8 + jj;
                    khi[so] = __float2bfloat16(v);
                }
            }
        }
    }
}

// ---------------------------------------------------------------------------
// Kernel B: MFMA scan over an m-quarter (512 cols). Per lane: two independent
// sorted depth-12 key lists (2-way ILP); owner (quad0) 8-way tournament merge
// -> top-24 -> wsk. khi fragment-swizzled (contiguous 1KB/wave loads).
// ---------------------------------------------------------------------------
__global__ __launch_bounds__(256, 4) void k_scan(
    const float* __restrict__ qf, const __hip_bfloat16* __restrict__ khi,
    unsigned* __restrict__ wsk)
{
    __shared__ unsigned kd[64*97];     // 24.8KB; row stride 97 (odd) bank-safe

    const int tid   = threadIdx.x;
    const int stile = blockIdx.x;      // 0..31
    const int hb    = blockIdx.y;      // 0..15
    const int mq    = blockIdx.z;      // 0..3

    const int lane = tid & 63;
    const int w    = tid >> 6;
    const int m16  = lane & 15;
    const int quad = lane >> 4;

    const size_t slab = (size_t)hb * 2048;
    const __hip_bfloat16* slabp = khi + (size_t)hb * 262144;   // swizzled slab

    const int sg_my = stile*64 + w*16 + m16;

    // Q fragment (B operand): B[n=m16][k=quad*8+j+ks*32] = q[w*16+n][k]
    short8v bq_[4];
    {
        const float* qp = qf + (slab + sg_my)*128 + quad*8;
        #pragma unroll
        for (int ks = 0; ks < 4; ++ks) {
            const float4 x0 = *(const float4*)(qp + ks*32);
            const float4 x1 = *(const float4*)(qp + ks*32 + 4);
            short8v tt;
            tt[0]=f2bf_s(x0.x); tt[1]=f2bf_s(x0.y); tt[2]=f2bf_s(x0.z); tt[3]=f2bf_s(x0.w);
            tt[4]=f2bf_s(x1.x); tt[5]=f2bf_s(x1.y); tt[6]=f2bf_s(x1.z); tt[7]=f2bf_s(x1.w);
            bq_[ks] = tt;
        }
    }

    unsigned KA[12], KB[12];           // ascending; [0] = min
    #pragma unroll
    for (int n = 0; n < 12; ++n) { KA[n] = 0u; KB[n] = 0u; }

    #pragma unroll 1
    for (int cti = 0; cti < 32; ++cti) {
        const int T = mq*32 + cti;     // global 16-col tile id
        const __hip_bfloat16* kp = slabp + (size_t)T*2048 + lane*8;
        float4v acc = (float4v){0.f,0.f,0.f,0.f};
        #pragma unroll
        for (int ks = 0; ks < 4; ++ks) {
            const short8v ka = *(const short8v*)(kp + ks*512);
            acc = __builtin_amdgcn_mfma_f32_16x16x32_bf16(ka, bq_[ks], acc, 0, 0, 0);
        }
        const int cb = T*16 + quad*4;
        #pragma unroll
        for (int ph = 0; ph < 2; ++ph) {
            {   // KA insert: reg = ph
                const int m = cb + ph;
                unsigned key = (mono(acc[ph]) & 0xFFFFF800u) | (unsigned)m;
                key = (m == sg_my) ? 0u : key;
                KA[0] = umax_(KA[0], key);
                #pragma unroll
                for (int i = 0; i < 11; ++i) {
                    const unsigned a = KA[i], c = KA[i+1];
                    KA[i]   = umin_(a, c);
                    KA[i+1] = umax_(a, c);
                }
            }
            {   // KB insert: reg = 2+ph
                const int m = cb + 2 + ph;
                unsigned key = (mono(acc[2+ph]) & 0xFFFFF800u) | (unsigned)m;
                key = (m == sg_my) ? 0u : key;
                KB[0] = umax_(KB[0], key);
                #pragma unroll
                for (int i = 0; i < 11; ++i) {
                    const unsigned a = KB[i], c = KB[i+1];
                    KB[i]   = umin_(a, c);
                    KB[i+1] = umax_(a, c);
                }
            }
        }
    }

    // dump: per (row, quad) two desc 12-lists
    const int rr = w*16 + m16;
    #pragma unroll
    for (int n = 0; n < 12; ++n) {
        kd[rr*97 + (quad*2 + 0)*12 + n] = KA[11 - n];
        kd[rr*97 + (quad*2 + 1)*12 + n] = KB[11 - n];
    }
    __syncthreads();

    // owner (quad 0): 8-way tournament merge -> top-24 -> ws (desc).
    if (quad == 0) {
        const unsigned* R = &kd[rr*97];
        int q0=0,q1=0,q2=0,q3=0,q4=0,q5=0,q6=0,q7=0;
        const size_t base = (size_t)hb*2048 + stile*64 + rr;
        #pragma unroll 1
        for (int n = 0; n < 24; ++n) {
            const unsigned h0 = (q0<12)?R[  0+q0]:0u;
            const unsigned h1 = (q1<12)?R[ 12+q1]:0u;
            const unsigned h2 = (q2<12)?R[ 24+q2]:0u;
            const unsigned h3 = (q3<12)?R[ 36+q3]:0u;
            const unsigned h4 = (q4<12)?R[ 48+q4]:0u;
            const unsigned h5 = (q5<12)?R[ 60+q5]:0u;
            const unsigned h6 = (q6<12)?R[ 72+q6]:0u;
            const unsigned h7 = (q7<12)?R[ 84+q7]:0u;
            unsigned bv = h0; int bs = 0;
            if (h1 > bv) { bv = h1; bs = 1; }
            if (h2 > bv) { bv = h2; bs = 2; }
            if (h3 > bv) { bv = h3; bs = 3; }
            if (h4 > bv) { bv = h4; bs = 4; }
            if (h5 > bv) { bv = h5; bs = 5; }
            if (h6 > bv) { bv = h6; bs = 6; }
            if (h7 > bv) { bv = h7; bs = 7; }
            q0 += (bs==0); q1 += (bs==1); q2 += (bs==2); q3 += (bs==3);
            q4 += (bs==4); q5 += (bs==5); q6 += (bs==6); q7 += (bs==7);
            wsk[(size_t)(mq*24 + n)*32768 + base] = bv;
        }
    }
}

// ---------------------------------------------------------------------------
// Kernel C: per row merge 4x24 approx keys -> top-32 -> cooperative exact
// fp32 rescore (pk-packed partials) -> exact top-20 -> quantiles + outputs.
// ---------------------------------------------------------------------------
__global__ __launch_bounds__(256, 4) void k_select(
    const float* __restrict__ qf, const float* __restrict__ kf,
    const unsigned* __restrict__ wsk,
    const float* __restrict__ errors, const float* __restrict__ y,
    const float* __restrict__ y_pred,
    float* __restrict__ out, float* __restrict__ hacc)
{
    __shared__ unsigned kd[64*4*25];       // 25.6KB (pad 25)
    __shared__ unsigned short cb[64*33];   // 4.2KB candidate cols
    __shared__ float es[64*33];            // 8.4KB exact scores
    __shared__ float ebuf[64*21];          // 5.4KB sort buffer

    const int tid   = threadIdx.x;
    const int stile = blockIdx.x;          // 0..31
    const int hb    = blockIdx.y;          // 0..15
    const int b     = hb >> 2;
    const int h     = hb & 3;

    const int lane = tid & 63;
    const int w    = tid >> 6;
    const int m16  = lane & 15;
    const int quad = lane >> 4;
    const int rr   = w*16 + m16;
    const int sg   = stile*64 + rr;

    const size_t base = (size_t)hb*2048 + sg;
    #pragma unroll 1
    for (int n = 0; n < 24; ++n)
        kd[(rr*4 + quad)*25 + n] = wsk[(size_t)(quad*24 + n)*32768 + base];
    __syncthreads();

    // owner: merge 4 sorted-desc 24-lists -> approx-top-32 cols
    if (quad == 0) {
        const unsigned* L0 = &kd[(rr*4 + 0)*25];
        const unsigned* L1 = &kd[(rr*4 + 1)*25];
        const unsigned* L2 = &kd[(rr*4 + 2)*25];
        const unsigned* L3 = &kd[(rr*4 + 3)*25];
        int p0 = 0, p1 = 0, p2 = 0, p3 = 0;
        #pragma unroll 1
        for (int n = 0; n < 32; ++n) {
            const unsigned h0 = (p0 < 24) ? L0[p0] : 0u;
            const unsigned h1 = (p1 < 24) ? L1[p1] : 0u;
            const unsigned h2 = (p2 < 24) ? L2[p2] : 0u;
            const unsigned h3 = (p3 < 24) ? L3[p3] : 0u;
            unsigned bv = h0; int bs = 0;
            if (h1 > bv) { bv = h1; bs = 1; }
            if (h2 > bv) { bv = h2; bs = 2; }
            if (h3 > bv) { bv = h3; bs = 3; }
            if (bs == 0) ++p0; else if (bs == 1) ++p1; else if (bs == 2) ++p2; else ++p3;
            cb[rr*33 + n] = (unsigned short)(bv & 0x7FFu);
        }
    }
    __syncthreads();

    // cooperative exact rescore of the 32 candidates (pk-packed partials)
    const size_t slab = (size_t)hb * 2048;
    const float* qrow_p = qf + (slab + sg)*128;
    float4 qseg[8];
    #pragma unroll
    for (int u = 0; u < 8; ++u)
        qseg[u] = *(const float4*)(qrow_p + quad*4 + u*16);
    const float* kslab = kf + slab*128;
    #pragma unroll 1
    for (int n = 0; n < 32; ++n) {
        const int col = cb[rr*33 + n];
        const float* kc = kslab + (size_t)col*128 + quad*4;
        float2v s01 = (float2v){0.f, 0.f}, s23 = (float2v){0.f, 0.f};
        #pragma unroll
        for (int u = 0; u < 8; ++u) {
            const float4 kv = *(const float4*)(kc + u*16);
            s01 = __builtin_elementwise_fma((float2v){qseg[u].x, qseg[u].y},
                                            (float2v){kv.x, kv.y}, s01);
            s23 = __builtin_elementwise_fma((float2v){qseg[u].z, qseg[u].w},
                                            (float2v){kv.z, kv.w}, s23);
        }
        float v = (s01[0] + s01[1]) + (s23[0] + s23[1]);
        v += __shfl_xor(v, 16);
        v += __shfl_xor(v, 32);
        if (quad == 0) es[rr*33 + n] = v;
    }

    // owner: exact top-20 selection (desc, col asc ties) + quantiles
    float sq = 0.f;
    if (quad == 0) {
        float* e = &ebuf[rr*21];
        #pragma unroll 1
        for (int k = 0; k < 20; ++k) {
            float best = -INFINITY; int bc = 4096, bj = 0;
            #pragma unroll 1
            for (int j = 0; j < 32; ++j) {
                const float v = es[rr*33 + j];
                const int c = cb[rr*33 + j];
                if (v > best || (v == best && c < bc)) { best = v; bc = c; bj = j; }
            }
            es[rr*33 + bj] = -INFINITY;
            e[k] = errors[((size_t)(b*SS + bc))*4];   // errors[..., 0]
        }
        #pragma unroll 1
        for (int a = 1; a < 20; ++a) {     // insertion sort ascending
            const float v = e[a];
            int n = a;
            while (n > 0 && e[n-1] > v) { e[n] = e[n-1]; --n; }
            e[n] = v;
        }
        const float yp = y_pred[((size_t)(b*SS + sg))*4];
        const float yt = y[((size_t)(b*SS + sg))*4];
        float msum = 0.f;
        const size_t obase = ((size_t)(h*4 + b)*18)*2048 + sg;
        #pragma unroll 1
        for (int a = 0; a < 18; ++a) {
            const float alpha = c_alphas[a];
            const float beta  = 0.5f*alpha;
            const float pl = beta * 19.f;
            const int   il = (int)pl;
            const float fl = pl - (float)il;
            const float ql = e[il]*(1.f-fl) + e[il+1]*fl;
            const float qq = (1.f - alpha) + beta;
            const float ph = qq * 19.f;
            const int   ih = (int)ph;
            const float fh = ph - (float)ih;
            const float qh = e[ih]*(1.f-fh) + e[ih+1]*fh;
            msum += ql + qh;
            const size_t oidx = obase + (size_t)a*2048;
            out[OFF_YLOW  + oidx] = ql + yp;
            out[OFF_YHIGH + oidx] = qh + yp;
            out[OFF_QLOW  + oidx] = ql;
            out[OFF_QHIGH + oidx] = qh;
        }
        const float me = msum * (1.f/36.f);
        const float dd = yt - (me + yp);
        sq = dd*dd;
    }
    // wave-reduce sq (non-owners contribute 0), one atomic per wave
    #pragma unroll
    for (int o = 32; o > 0; o >>= 1) sq += __shfl_xor(sq, o);
    if (lane == 0) atomicAdd(&hacc[h], sq);
}

__global__ void k_init(float* __restrict__ hacc) {
    if (threadIdx.x < 4) hacc[threadIdx.x] = 0.f;
}

__global__ __launch_bounds__(256) void k_finalize(
    const float* __restrict__ y, const float* __restrict__ y_pred,
    const float* __restrict__ errors, const float* __restrict__ hacc,
    float* __restrict__ out)
{
    const int i = blockIdx.x*256 + threadIdx.x;
    if (i == 0)
        out[0] = (hacc[0]+hacc[1]+hacc[2]+hacc[3]) * (1.f/32768.f);
    if (i < 32768)      out[OFF_Y + i] = y[i];
    else if (i < 65536) out[OFF_YPRED + (i - 32768)] = y_pred[i - 32768];
    else if (i < 73728) { const int j = i - 65536; out[OFF_ERR + j] = errors[(size_t)j*4]; }
}

extern "C" void kernel_launch(void* const* d_in, const int* in_sizes, int n_in,
                              void* d_out, int out_size, void* d_ws, size_t ws_size,
                              hipStream_t stream)
{
    const float* Xt     = (const float*)d_in[0];
    const float* Xs     = (const float*)d_in[1];
    const float* errors = (const float*)d_in[2];
    const float* y      = (const float*)d_in[3];
    const float* y_pred = (const float*)d_in[4];
    const float* W1 = (const float*)d_in[5];   const float* b1 = (const float*)d_in[6];
    const float* W2 = (const float*)d_in[7];   const float* b2 = (const float*)d_in[8];
    const float* W3 = (const float*)d_in[9];   const float* b3 = (const float*)d_in[10];
    const float* W4 = (const float*)d_in[11];  const float* b4 = (const float*)d_in[12];
    const float* Wq = (const float*)d_in[13];  const float* bq = (const float*)d_in[14];
    const float* Wk = (const float*)d_in[15];  const float* bk = (const float*)d_in[16];
    const float* g_q    = (const float*)d_in[17];
    const float* beta_q = (const float*)d_in[18];
    const float* g_k    = (const float*)d_in[19];
    const float* beta_k = (const float*)d_in[20];

    float* out  = (float*)d_out;
    char*  base = (char*)d_ws;
    const size_t SLAB = (size_t)16*2048*128;               // 4,194,304 elements
    float* hacc = (float*)base;                            // 64B slot
    float* qf   = (float*)(base + 256);                    // 16MB
    float* kf   = qf + SLAB;                               // 16MB
    __hip_bfloat16* khi = (__hip_bfloat16*)(kf + SLAB);    // 8MB (swizzled)
    unsigned* wsk = (unsigned*)(khi + SLAB);               // 12.6MB

    k_init<<<1, 64, 0, stream>>>(hacc);
    k_mlp<<<2048, 64, 0, stream>>>(Xt, Xs, W1,b1,W2,b2,W3,b3,W4,b4,
                                   Wq,bq,Wk,bk,g_q,beta_q,g_k,beta_k,
                                   qf, kf, khi);
    k_scan<<<dim3(32,16,4), 256, 0, stream>>>(qf, khi, wsk);
    k_select<<<dim3(32,16), 256, 0, stream>>>(qf, kf, wsk, errors, y, y_pred, out, hacc);
    k_finalize<<<288, 256, 0, stream>>>(y, y_pred, errors, hacc, out);
}